// Round 12
// baseline (288.879 us; speedup 1.0000x reference)
//
// RINet fused — R12: revert R11 gather (uncoalesced L2 in CB loop = -33%),
// persistent 512-block main with register-prefetch pipeline across iters.
// Journal: R1 3762 | R2 505 | R3 312 | R4 253 | R5 260 spill | R6 243 |
// R7 181.8 | R8 186.9 spill | R9 FAIL | R10 159.1 (main 114, occ 39%) |
// R11 196 REGRESSION (fs gather direct-from-L2 in CB critical path).
// R12: R10 structure; main is persistent: 512 blocks x 8 iters (2 pos/iter);
// next iter's gather+sipf loaded to REGISTERS right after CB mfmas (latency
// hides under kk/qv/D/nextA); P~ aliases qT (T2, R11-verified) so T1 is free
// for next staging. +~20 VGPR. Tripwire: main WRITE_SIZE >> 6MB = spill.
#include <hip/hip_runtime.h>

#define B_    8
#define N_    1024
#define K_    32
#define CIN   128
#define COUT  256
#define EPSF  1e-5f
#define NEG   0.2f

// ws float offsets
#define WS_MP   0          // 256 blocks x 48 (44 used) moment partials
#define WS_ESUM 12288      // 256
#define WS_ESS  12544      // 256
#define WS_BK   12800      // 128
#define WS_BV   12928      // 128
// ws byte offsets
#define WB_BYTE 53248
#define XT_BYTE 331776     // WB + 278528
#define Y_BYTE  2428928    // XT + 2MB   (total ~4.43MB)
// short offsets inside wb
#define WQB   0
#define WVB   16384
#define WK2B  32768
#define WV2B  49152
#define WEB   65536
#define WK1F  131072
#define WV1F  135168

typedef unsigned short ushort_t;
typedef unsigned int   uint_t;
typedef __attribute__((ext_vector_type(8))) short s8v;
typedef __attribute__((ext_vector_type(4))) short s4v;
typedef __attribute__((ext_vector_type(4))) float f4v;
typedef __bf16 bf16x8 __attribute__((ext_vector_type(8)));

constexpr int   P_TOT  = B_ * N_ * K_;
constexpr float INV_P  = 1.0f / (float)P_TOT;
constexpr float INV_BN = 1.0f / (float)(B_ * N_);

__device__ __forceinline__ float b2f(ushort_t u) {
    return __uint_as_float(((uint_t)u) << 16);
}
__device__ __forceinline__ ushort_t f2b(float f) {
    return __builtin_bit_cast(ushort_t, (__bf16)f);
}
__device__ __forceinline__ bf16x8 ld8(const ushort_t* p) {
    return __builtin_bit_cast(bf16x8, *(const s8v*)p);
}
__device__ __forceinline__ int qx2(int c, int k) {       // v-tile swizzle
    return (c * 32 + k) ^ (((c >> 1) & 7) << 3);
}

// ---------------------------------------------------------------------------
// prep: moments partials (blk<256) | xT bf16 coalesced (256..511) |
//       weights bf16 + ESUM/ESS zero (512..639)
// ---------------------------------------------------------------------------
__global__ __launch_bounds__(256) void prep_kernel(
    const float* __restrict__ x, const float* __restrict__ SiPF,
    const float* __restrict__ w_kv, const float* __restrict__ wk2,
    const float* __restrict__ wv2, const float* __restrict__ we,
    float* __restrict__ ws, ushort_t* __restrict__ wb,
    ushort_t* __restrict__ xT)
{
    __shared__ float red[4][44];
    __shared__ float tile[32][129];
    const int blk = blockIdx.x;
    const int t   = threadIdx.x;

    if (blk < 256) {                                 // ---- moment partials
        float s1[8], s2[36];
#pragma unroll
        for (int i = 0; i < 8; ++i) s1[i] = 0.f;
#pragma unroll
        for (int i = 0; i < 36; ++i) s2[i] = 0.f;
        const int tid = blk * 256 + t;
#pragma unroll
        for (int it = 0; it < P_TOT / 65536; ++it) {
            const float4* base = (const float4*)(SiPF + (size_t)(tid + it * 65536) * 8);
            float4 a = base[0], bq = base[1];
            float v[8] = {a.x, a.y, a.z, a.w, bq.x, bq.y, bq.z, bq.w};
            int idx = 0;
#pragma unroll
            for (int i = 0; i < 8; ++i) {
                s1[i] += v[i];
#pragma unroll
                for (int j = i; j < 8; ++j) s2[idx++] += v[i] * v[j];
            }
        }
#pragma unroll
        for (int i = 0; i < 8; ++i)
            for (int m = 32; m; m >>= 1) s1[i] += __shfl_xor(s1[i], m);
#pragma unroll
        for (int i = 0; i < 36; ++i)
            for (int m = 32; m; m >>= 1) s2[i] += __shfl_xor(s2[i], m);
        if ((t & 63) == 0) {
            const int w = t >> 6;
#pragma unroll
            for (int i = 0; i < 8; ++i) red[w][i] = s1[i];
#pragma unroll
            for (int i = 0; i < 36; ++i) red[w][8 + i] = s2[i];
        }
        __syncthreads();
        if (t < 44)
            ws[WS_MP + blk * 48 + t] = red[0][t] + red[1][t] + red[2][t] + red[3][t];
    } else if (blk < 512) {                          // ---- x -> xT bf16
        const int tb = blk - 256;
        const int b  = tb >> 5;
        const int n0 = (tb & 31) << 5;
        const int cgr = t >> 5, n = t & 31;
#pragma unroll
        for (int i = 0; i < 16; ++i) {
            const int c = cgr * 16 + i;
            tile[n][c] = x[((size_t)(b * CIN + c)) * N_ + n0 + n];
        }
        __syncthreads();
        const int nr = t >> 3, c0 = (t & 7) * 16;
        s8v o0, o1;
#pragma unroll
        for (int j = 0; j < 8; ++j) {
            o0[j] = (short)f2b(tile[nr][c0 + j]);
            o1[j] = (short)f2b(tile[nr][c0 + 8 + j]);
        }
        s8v* dst = (s8v*)(xT + ((size_t)(b * N_ + n0 + nr)) * 128 + c0);
        dst[0] = o0; dst[1] = o1;
    } else {                                         // ---- weights -> bf16
        if (blk == 512) {                            // zero bne accumulators
            ws[WS_ESUM + t] = 0.f;
            ws[WS_ESS + t]  = 0.f;
        }
        const int base = (blk - 512) * 1024 + t;
#pragma unroll
        for (int i = 0; i < 4; ++i) {
            const int e = base + i * 256;
            float v;
            if (e < 32768)      v = w_kv[e];
            else if (e < 49152) v = wk2[e - 32768];
            else if (e < 65536) v = wv2[e - 49152];
            else                v = we[e - 65536];
            wb[e] = f2b(v);
        }
    }
}

// ---------------------------------------------------------------------------
// prep2: reduce moment partials, BN-fold coeffs, folded bf16 wk1/wv1
// ---------------------------------------------------------------------------
__global__ __launch_bounds__(128) void prep2_kernel(
    const float* __restrict__ wk1, const float* __restrict__ wv1,
    const float* __restrict__ bnk_gamma, const float* __restrict__ bnk_beta,
    const float* __restrict__ bnv_gamma, const float* __restrict__ bnv_beta,
    float* __restrict__ ws, ushort_t* __restrict__ wb)
{
    __shared__ float red2[44];
    const int c = threadIdx.x;
    if (c < 44) {
        float s = 0.f;
        for (int bq = 0; bq < 256; ++bq) s += ws[WS_MP + bq * 48 + c];
        red2[c] = s;
    }
    __syncthreads();

    float m1[8], wkr[8], wvr[8];
#pragma unroll
    for (int s = 0; s < 8; ++s) {
        m1[s]  = red2[s] * INV_P;
        wkr[s] = wk1[c * 8 + s];
        wvr[s] = wv1[c * 8 + s];
    }
    float mk = 0.f, mv = 0.f;
#pragma unroll
    for (int s = 0; s < 8; ++s) { mk += wkr[s] * m1[s]; mv += wvr[s] * m1[s]; }
    float ek = 0.f, ev = 0.f;
#pragma unroll
    for (int s = 0; s < 8; ++s)
#pragma unroll
        for (int s2 = 0; s2 < 8; ++s2) {
            const int i = s < s2 ? s : s2;
            const int j = s < s2 ? s2 : s;
            const float m2 = red2[8 + 8 * i - (i * (i - 1)) / 2 + (j - i)] * INV_P;
            ek += wkr[s] * wkr[s2] * m2;
            ev += wvr[s] * wvr[s2] * m2;
        }
    const float Ak = bnk_gamma[c] * rsqrtf(ek - mk * mk + EPSF);
    const float Av = bnv_gamma[c] * rsqrtf(ev - mv * mv + EPSF);
    ws[WS_BK + c] = bnk_beta[c] - mk * Ak;           // bv1 cancels in BN
    ws[WS_BV + c] = bnv_beta[c] - mv * Av;
#pragma unroll
    for (int s = 0; s < 32; ++s) {
        wb[WK1F + c * 32 + s] = s < 8 ? f2b(Ak * wkr[s]) : (ushort_t)0;
        wb[WV1F + c * 32 + s] = s < 8 ? f2b(Av * wvr[s]) : (ushort_t)0;
    }
}

// ---------------------------------------------------------------------------
// main: persistent, 512 blocks x 8 iters; 512 thr / 8 waves; 2 pos per iter.
// LDS 64 KB (T1..T4 x 2 pos) -> 2 blocks/CU. Next iter's gather+sipf
// prefetched to registers after CB mfmas. P~ aliases qT (T2).
// ---------------------------------------------------------------------------
__global__ __launch_bounds__(512, 4) void main_kernel(
    const float* __restrict__ SiPF, const float* __restrict__ bv2,
    const int* __restrict__ col,    const float* __restrict__ ws,
    const ushort_t* __restrict__ wb, const ushort_t* __restrict__ xT,
    ushort_t* __restrict__ y)
{
    __shared__ __align__(16) ushort_t T1[2][4096];   // fsT [k][c]
    __shared__ __align__(16) ushort_t T2[2][4096];   // hkT; qT; then P~
    __shared__ __align__(16) ushort_t T3[2][4096];   // hvT; then v [c][k]
    __shared__ __align__(16) ushort_t T4[2][4096];   // sipf head; then kkT

    const int bid = blockIdx.x;                      // 512 blocks
    const int t   = threadIdx.x;
    const int wv_ = t >> 6, l = t & 63, lr = l & 15, lg = l >> 4;
    const int cw  = wv_ * 16;
    const int p   = t >> 8;                          // staging position half
    const int tt  = t & 255, k = tt & 31, cg = tt >> 5;
    const f4v z4 = {0.f, 0.f, 0.f, 0.f};

    // staging registers (filled for iter 0 now, iter i+1 during iter i)
    s8v    f0n, f1n;
    float4 sp0n = {0,0,0,0}, sp1n = {0,0,0,0};
    {
        const int bn   = bid * 16 + p;               // pi = bid*8, 2 pos
        const int b    = bn >> 10;
        const int idxk = col[bn * K_ + k] - b * N_;
        const s8v* xrow = (const s8v*)(xT + ((size_t)(b << 10) + idxk) * 128 + cg * 16);
        f0n = xrow[0]; f1n = xrow[1];
        if (cg == 0) {
            const float4* sp = (const float4*)(SiPF + (size_t)bn * 256 + k * 8);
            sp0n = sp[0]; sp1n = sp[1];
        }
    }

    for (int it = 0; it < 8; ++it) {
        const int pi = bid * 8 + it;

        // ---- Phase A: staged regs -> LDS ----
        {
            const int base = k * 128 + cg * 16;
            const int sw   = (k & 7) << 3;
            *(s8v*)&T1[p][(base) ^ sw]     = f0n;
            *(s8v*)&T1[p][(base + 8) ^ sw] = f1n;
            if (cg < 4) {
                const int slot = (cg * 8) ^ ((k & 3) << 3);
                s8v o8 = {0, 0, 0, 0, 0, 0, 0, 0};
                if (cg == 0) {
                    o8[0] = (short)f2b(sp0n.x); o8[1] = (short)f2b(sp0n.y);
                    o8[2] = (short)f2b(sp0n.z); o8[3] = (short)f2b(sp0n.w);
                    o8[4] = (short)f2b(sp1n.x); o8[5] = (short)f2b(sp1n.y);
                    o8[6] = (short)f2b(sp1n.z); o8[7] = (short)f2b(sp1n.w);
                }
                *(s8v*)&T4[p][k * 32 + slot] = o8;
            }
        }
        __syncthreads();

        // ---- Phase A2: hk/hv both positions ----
        {
            bf16x8 sb[4];
#pragma unroll
            for (int nt = 0; nt < 4; ++nt) {
                const int pp  = nt >> 1;
                const int row = (nt & 1) * 16 + lr;
                sb[nt] = ld8(&T4[pp][row * 32 + ((lg * 8) ^ ((row & 3) << 3))]);
            }
            const float4 bka = *(const float4*)&ws[WS_BK + cw + lg * 4];
            const float4 bva = *(const float4*)&ws[WS_BV + cw + lg * 4];
            const float Bk_[4] = {bka.x, bka.y, bka.z, bka.w};
            const float Bv_[4] = {bva.x, bva.y, bva.z, bva.w};
            const bf16x8 a1 = ld8(&wb[WK1F + (cw + lr) * 32 + lg * 8]);
            const bf16x8 a2 = ld8(&wb[WV1F + (cw + lr) * 32 + lg * 8]);
            f4v hka[4], hva[4];
#pragma unroll
            for (int nt = 0; nt < 4; ++nt) {
                hka[nt] = __builtin_amdgcn_mfma_f32_16x16x32_bf16(a1, sb[nt], z4, 0, 0, 0);
                hva[nt] = __builtin_amdgcn_mfma_f32_16x16x32_bf16(a2, sb[nt], z4, 0, 0, 0);
            }
#pragma unroll
            for (int nt = 0; nt < 4; ++nt) {
                const int pp  = nt >> 1;
                const int c0  = cw + lg * 4;
                const int kc  = (nt & 1) * 16 + lr;
                const int idx = (kc * 128 + c0) ^ ((kc & 7) << 3);
                s4v hk4, hv4;
#pragma unroll
                for (int r = 0; r < 4; ++r) {
                    hk4[r] = (short)f2b(fmaxf(hka[nt][r] + Bk_[r], 0.f));
                    hv4[r] = (short)f2b(fmaxf(hva[nt][r] + Bv_[r], 0.f));
                }
                *(s4v*)&T2[pp][idx] = hk4;
                *(s4v*)&T3[pp][idx] = hv4;
            }
        }
        __syncthreads();

        // ---- Phase CB: 4 GEMMs x N=64, 64 MFMA/wave ----
        f4v ck[4], cs[4], aq[4], av[4];
#pragma unroll
        for (int nt = 0; nt < 4; ++nt) { ck[nt] = z4; cs[nt] = z4; aq[nt] = z4; av[nt] = z4; }
        __builtin_amdgcn_s_setprio(1);
#pragma unroll
        for (int kt = 0; kt < 4; ++kt) {
            const int cp0 = kt * 32 + lg * 8;
            bf16x8 bk[4], bv[4], bfr[4];
#pragma unroll
            for (int nt = 0; nt < 4; ++nt) {
                const int pp  = nt >> 1;
                const int kk_ = (nt & 1) * 16 + lr;
                const int idx = (kk_ * 128 + cp0) ^ ((lr & 7) << 3);
                bk[nt]  = ld8(&T2[pp][idx]);
                bv[nt]  = ld8(&T3[pp][idx]);
                bfr[nt] = ld8(&T1[pp][idx]);
            }
            const int c = cw + lr;
            const bf16x8 a1 = ld8(&wb[WK2B + c * 128 + cp0]);
            const bf16x8 a2 = ld8(&wb[WV2B + c * 128 + cp0]);
            const bf16x8 a3 = ld8(&wb[WQB  + c * 128 + cp0]);
            const bf16x8 a4 = ld8(&wb[WVB  + c * 128 + cp0]);
#pragma unroll
            for (int nt = 0; nt < 4; ++nt) {
                ck[nt] = __builtin_amdgcn_mfma_f32_16x16x32_bf16(a1, bk[nt],  ck[nt], 0, 0, 0);
                cs[nt] = __builtin_amdgcn_mfma_f32_16x16x32_bf16(a2, bv[nt],  cs[nt], 0, 0, 0);
                aq[nt] = __builtin_amdgcn_mfma_f32_16x16x32_bf16(a3, bfr[nt], aq[nt], 0, 0, 0);
                av[nt] = __builtin_amdgcn_mfma_f32_16x16x32_bf16(a4, bfr[nt], av[nt], 0, 0, 0);
            }
        }
        __builtin_amdgcn_s_setprio(0);

        // ---- prefetch next iter's staging (registers; latency hides) ----
        if (it < 7) {
            const int bnn  = (pi + 1) * 2 + p;
            const int bb   = bnn >> 10;
            const int idxn = col[bnn * K_ + k] - bb * N_;
            const s8v* xr2 = (const s8v*)(xT + ((size_t)(bb << 10) + idxn) * 128 + cg * 16);
            f0n = xr2[0]; f1n = xr2[1];
            if (cg == 0) {
                const float4* sp = (const float4*)(SiPF + (size_t)bnn * 256 + k * 8);
                sp0n = sp[0]; sp1n = sp[1];
            }
        }

        // kk -> T4 (sipf dead since A2 barrier)
#pragma unroll
        for (int nt = 0; nt < 4; ++nt) {
            const int pp  = nt >> 1;
            const int c0  = cw + lg * 4;
            const int kk_ = (nt & 1) * 16 + lr;
            const int idx = (kk_ * 128 + c0) ^ ((kk_ & 7) << 3);
            s4v ck4;
#pragma unroll
            for (int r = 0; r < 4; ++r) ck4[r] = (short)f2b(ck[nt][r]);
            *(s4v*)&T4[pp][idx] = ck4;
        }
        __syncthreads();   // all T1/T2/T3 reads complete

        // ---- q -> T2 (scaled), v = vfs*(cs+bv2) -> T3 ----
        {
            const float4 bvv = *(const float4*)&bv2[cw + lg * 4];
            const float bv2_[4] = {bvv.x, bvv.y, bvv.z, bvv.w};
            const float SC = 0.17677669529663687f;   // 1/sqrt(32)
#pragma unroll
            for (int nt = 0; nt < 4; ++nt) {
                const int pp  = nt >> 1;
                const int c0  = cw + lg * 4;
                const int kk_ = (nt & 1) * 16 + lr;
                const int idx = (kk_ * 128 + c0) ^ ((kk_ & 7) << 3);
                s4v q4;
#pragma unroll
                for (int r = 0; r < 4; ++r) {
                    q4[r] = (short)f2b(aq[nt][r] * SC);
                    T3[pp][qx2(c0 + r, kk_)] =
                        f2b(av[nt][r] * (cs[nt][r] + bv2_[r]));
                }
                *(s4v*)&T2[pp][idx] = q4;
            }
        }
        __syncthreads();

        // ---- Phase D: attention, wave -> (position, head) ----
        {
            const int pp = wv_ >> 2;
            const int h  = wv_ & 3;
            const int bn = pi * 2 + pp;
            bf16x8 aqf[2], bkf[2];
#pragma unroll
            for (int mt = 0; mt < 2; ++mt)
                aqf[mt] = ld8(&T2[pp][((mt * 16 + lr) * 128 + h * 32 + lg * 8) ^ ((lr & 7) << 3)]);
#pragma unroll
            for (int nt = 0; nt < 2; ++nt)
                bkf[nt] = ld8(&T4[pp][((nt * 16 + lr) * 128 + h * 32 + lg * 8) ^ ((lr & 7) << 3)]);
            f4v s[2][2];
#pragma unroll
            for (int mt = 0; mt < 2; ++mt)
#pragma unroll
                for (int nt = 0; nt < 2; ++nt)
                    s[mt][nt] = __builtin_amdgcn_mfma_f32_16x16x32_bf16(aqf[mt], bkf[nt], z4, 0, 0, 0);

            __syncthreads();   // closes all qT (T2) + kkT (T4) reads

            // P~ = exp(s) unnormalized -> T2 (aliases qT region)
            ushort_t* P = &T2[pp][h * 1024];
#pragma unroll
            for (int mt = 0; mt < 2; ++mt)
#pragma unroll
                for (int nt = 0; nt < 2; ++nt) {
                    const int kq0 = mt * 16 + lg * 4;
                    const int j   = nt * 16 + lr;
#pragma unroll
                    for (int r = 0; r < 4; ++r) {
                        const int kq = kq0 + r;
                        P[(kq * 32 + j) ^ ((kq & 7) << 3)] = f2b(__expf(s[mt][nt][r]));
                    }
                }

            bf16x8 af[2], pb[2];
#pragma unroll
            for (int mt2 = 0; mt2 < 2; ++mt2)
                af[mt2] = ld8(&T3[pp][qx2(h * 32 + mt2 * 16 + lr, lg * 8)]);
#pragma unroll
            for (int nt2 = 0; nt2 < 2; ++nt2) {
                const int kq2 = nt2 * 16 + lr;
                pb[nt2] = ld8(&P[(kq2 * 32 + lg * 8) ^ ((lr & 7) << 3)]);
            }
            const s8v one8 = {(short)0x3F80, (short)0x3F80, (short)0x3F80, (short)0x3F80,
                              (short)0x3F80, (short)0x3F80, (short)0x3F80, (short)0x3F80};
            const bf16x8 ones = __builtin_bit_cast(bf16x8, one8);

            f4v o2[2][2], rsf[2];
            __builtin_amdgcn_s_setprio(1);
#pragma unroll
            for (int mt2 = 0; mt2 < 2; ++mt2)
#pragma unroll
                for (int nt2 = 0; nt2 < 2; ++nt2)
                    o2[mt2][nt2] = __builtin_amdgcn_mfma_f32_16x16x32_bf16(af[mt2], pb[nt2], z4, 0, 0, 0);
#pragma unroll
            for (int nt2 = 0; nt2 < 2; ++nt2)
                rsf[nt2] = __builtin_amdgcn_mfma_f32_16x16x32_bf16(ones, pb[nt2], z4, 0, 0, 0);
            __builtin_amdgcn_s_setprio(0);

            const float inv0 = 1.0f / rsf[0][0];
            const float inv1 = 1.0f / rsf[1][0];

            float ym[2][4];
#pragma unroll
            for (int mt2 = 0; mt2 < 2; ++mt2)
#pragma unroll
                for (int r = 0; r < 4; ++r)
                    ym[mt2][r] = fmaxf(o2[mt2][0][r] * inv0, o2[mt2][1][r] * inv1);
            // butterfly over lr bits only (lg lanes hold different channels)
#pragma unroll
            for (int m = 1; m <= 8; m <<= 1)
#pragma unroll
                for (int mt2 = 0; mt2 < 2; ++mt2)
#pragma unroll
                    for (int r = 0; r < 4; ++r)
                        ym[mt2][r] = fmaxf(ym[mt2][r], __shfl_xor(ym[mt2][r], m));
            if (lr == 0) {
#pragma unroll
                for (int mt2 = 0; mt2 < 2; ++mt2) {
                    unsigned long long pk = 0;
#pragma unroll
                    for (int r = 0; r < 4; ++r)
                        pk |= ((unsigned long long)f2b(ym[mt2][r])) << (16 * r);
                    *(unsigned long long*)&y[(size_t)bn * 128 + h * 32 + mt2 * 16 + lg * 4] = pk;
                }
            }
        }
        // next iter's Phase A barrier orders T1/T4-head overwrites
        __syncthreads();
    }
}

// ---------------------------------------------------------------------------
// zgemm: z = we_bf16 @ cat(y-x, x); raw z -> d_out + bne stats (atomics).
// ---------------------------------------------------------------------------
__global__ __launch_bounds__(256) void zgemm_kernel(
    const ushort_t* __restrict__ wb, const ushort_t* __restrict__ xT,
    const ushort_t* __restrict__ y, float* __restrict__ ws,
    float* __restrict__ out)
{
    __shared__ __align__(16) ushort_t Bt[32 * 256];  // [bn-local][c] swizzled
    const int blk = blockIdx.x;                      // 512 blocks
    const int bn0 = (blk >> 1) * 32;
    const int mh  = (blk & 1) * 128;
    const int t   = threadIdx.x;
    {
        const int r   = t >> 3;
        const int c0  = (t & 7) * 16;
        const int bnr = bn0 + r;
        const s8v* yr = (const s8v*)(y  + (size_t)bnr * 128 + c0);
        const s8v* xr = (const s8v*)(xT + (size_t)bnr * 128 + c0);
        const s8v y0 = yr[0], y1 = yr[1], x0 = xr[0], x1 = xr[1];
        s8v d0, d1;
#pragma unroll
        for (int j = 0; j < 8; ++j) {
            d0[j] = (short)f2b(b2f((ushort_t)y0[j]) - b2f((ushort_t)x0[j]));
            d1[j] = (short)f2b(b2f((ushort_t)y1[j]) - b2f((ushort_t)x1[j]));
        }
        const int sw = (r & 7) << 3;
        *(s8v*)&Bt[(r * 256 + c0) ^ sw]           = d0;
        *(s8v*)&Bt[(r * 256 + c0 + 8) ^ sw]       = d1;
        *(s8v*)&Bt[(r * 256 + 128 + c0) ^ sw]     = x0;
        *(s8v*)&Bt[(r * 256 + 128 + c0 + 8) ^ sw] = x1;
    }
    __syncthreads();

    const int w = t >> 6, l = t & 63, lr = l & 15, lg = l >> 4;
    const f4v z4 = {0.f, 0.f, 0.f, 0.f};
    f4v acc[2][2];
#pragma unroll
    for (int mt = 0; mt < 2; ++mt)
#pragma unroll
        for (int nt = 0; nt < 2; ++nt) acc[mt][nt] = z4;

#pragma unroll
    for (int kt = 0; kt < 8; ++kt) {
        const int kc = kt * 32 + lg * 8;
        bf16x8 bf[2];
#pragma unroll
        for (int nt = 0; nt < 2; ++nt) {
            const int rl = nt * 16 + lr;
            bf[nt] = ld8(&Bt[(rl * 256 + kc) ^ ((lr & 7) << 3)]);
        }
#pragma unroll
        for (int mt = 0; mt < 2; ++mt) {
            const int o = mh + w * 32 + mt * 16 + lr;
            const bf16x8 am = ld8(&wb[WEB + o * 256 + kc]);
#pragma unroll
            for (int nt = 0; nt < 2; ++nt)
                acc[mt][nt] = __builtin_amdgcn_mfma_f32_16x16x32_bf16(am, bf[nt], acc[mt][nt], 0, 0, 0);
        }
    }

    float sm[2][4], sq[2][4];
#pragma unroll
    for (int mt = 0; mt < 2; ++mt)
#pragma unroll
        for (int r = 0; r < 4; ++r) {
            const float a0 = acc[mt][0][r], a1 = acc[mt][1][r];
            sm[mt][r] = a0 + a1;
            sq[mt][r] = a0 * a0 + a1 * a1;
        }
#pragma unroll
    for (int m = 1; m <= 8; m <<= 1)
#pragma unroll
        for (int mt = 0; mt < 2; ++mt)
#pragma unroll
            for (int r = 0; r < 4; ++r) {
                sm[mt][r] += __shfl_xor(sm[mt][r], m);
                sq[mt][r] += __shfl_xor(sq[mt][r], m);
            }
    if (lr == 0) {
#pragma unroll
        for (int mt = 0; mt < 2; ++mt)
#pragma unroll
            for (int r = 0; r < 4; ++r) {
                const int o = mh + w * 32 + mt * 16 + lg * 4 + r;
                atomicAdd(&ws[WS_ESUM + o], sm[mt][r]);
                atomicAdd(&ws[WS_ESS + o],  sq[mt][r]);
            }
    }
    const int b = bn0 >> 10;
#pragma unroll
    for (int mt = 0; mt < 2; ++mt)
#pragma unroll
        for (int r = 0; r < 4; ++r) {
            const int o = mh + w * 32 + mt * 16 + lg * 4 + r;
#pragma unroll
            for (int nt = 0; nt < 2; ++nt) {
                const int n = (bn0 + nt * 16 + lr) & (N_ - 1);
                out[((size_t)(b * COUT + o)) * N_ + n] = acc[mt][nt][r];
            }
        }
}

// ---------------------------------------------------------------------------
// apply: in-place BN1d affine + leaky on d_out.
// ---------------------------------------------------------------------------
__global__ __launch_bounds__(256) void apply_kernel(
    const float* __restrict__ ws, const float* __restrict__ gamma,
    const float* __restrict__ beta, float* __restrict__ out)
{
    const int bo = blockIdx.x;                       // (b, o)
    const int o  = bo & 255;
    const int b  = bo >> 8;
    const float mean = ws[WS_ESUM + o] * INV_BN;
    const float var  = ws[WS_ESS + o] * INV_BN - mean * mean;
    const float A  = gamma[o] * rsqrtf(var + EPSF);
    const float Bb = beta[o] - mean * A;
    float4* p = (float4*)(out + ((size_t)(b * COUT + o)) * N_);
    float4 v = p[threadIdx.x];
    float r0 = A * v.x + Bb, r1 = A * v.y + Bb;
    float r2 = A * v.z + Bb, r3 = A * v.w + Bb;
    v.x = r0 >= 0.f ? r0 : NEG * r0;
    v.y = r1 >= 0.f ? r1 : NEG * r1;
    v.z = r2 >= 0.f ? r2 : NEG * r2;
    v.w = r3 >= 0.f ? r3 : NEG * r3;
    p[threadIdx.x] = v;
}

// ---------------------------------------------------------------------------
extern "C" void kernel_launch(void* const* d_in, const int* in_sizes, int n_in,
                              void* d_out, int out_size, void* d_ws, size_t ws_size,
                              hipStream_t stream)
{
    (void)in_sizes; (void)n_in; (void)out_size; (void)ws_size;

    const float* x         = (const float*)d_in[0];
    const float* SiPF      = (const float*)d_in[1];
    const float* w_kv      = (const float*)d_in[2];
    const float* wk1       = (const float*)d_in[3];
    const float* bnk_gamma = (const float*)d_in[4];
    const float* bnk_beta  = (const float*)d_in[5];
    const float* wk2       = (const float*)d_in[6];
    const float* wv1       = (const float*)d_in[7];
    // d_in[8] = bv1: cancels inside _bn2d — unused
    const float* bnv_gamma = (const float*)d_in[9];
    const float* bnv_beta  = (const float*)d_in[10];
    const float* wv2       = (const float*)d_in[11];
    const float* bv2       = (const float*)d_in[12];
    const float* we        = (const float*)d_in[13];
    const float* bne_gamma = (const float*)d_in[14];
    const float* bne_beta  = (const float*)d_in[15];
    const int*   col       = (const int*)d_in[16];

    float*    ws = (float*)d_ws;
    ushort_t* wb = (ushort_t*)((char*)d_ws + WB_BYTE);
    ushort_t* xT = (ushort_t*)((char*)d_ws + XT_BYTE);
    ushort_t* y  = (ushort_t*)((char*)d_ws + Y_BYTE);

    prep_kernel<<<640, 256, 0, stream>>>(x, SiPF, w_kv, wk2, wv2, we, ws, wb, xT);
    prep2_kernel<<<1, 128, 0, stream>>>(wk1, wv1, bnk_gamma, bnk_beta,
                                        bnv_gamma, bnv_beta, ws, wb);
    main_kernel<<<512, 512, 0, stream>>>(SiPF, bv2, col, ws, wb, xT, y);
    zgemm_kernel<<<512, 256, 0, stream>>>(wb, xT, y, ws, (float*)d_out);
    apply_kernel<<<2048, 256, 0, stream>>>(ws, bne_gamma, bne_beta,
                                           (float*)d_out);
}

// Round 13
// 261.339 us; speedup vs baseline: 1.1054x; 1.1054x over previous
//
// RINet fused — R13: revert main to R10 (R11/R12 both regressed; 64 VGPR +
// 64 AGPR accums = exactly the 128-reg/16-wave cliff -> occupancy path dead),
// cooperative zgemm with fused BN-apply (grid.sync), 1024 blocks.
// Journal: R1 3762 | R2 505 | R3 312 | R4 253 | R5 260 spill | R6 243 |
// R7 181.8 | R8 186.9 spill | R9 FAIL | R10 159.1 (main 114) | R11 196
// (uncoalesced gather in CB) | R12 289 (persistent-loop prefetch spilled:
// FETCH 666MB). R13: main = R10 verbatim. zgemm: 1024 blks (16bn x Mhalf),
// stats atomics -> this_grid().sync() -> normalize accs IN REGISTERS ->
// single d_out write with leaky. Kills apply kernel + z fp32 round-trip.
#include <hip/hip_runtime.h>
#include <hip/hip_cooperative_groups.h>
namespace cg = cooperative_groups;

#define B_    8
#define N_    1024
#define K_    32
#define CIN   128
#define COUT  256
#define EPSF  1e-5f
#define NEG   0.2f

// ws float offsets
#define WS_MP   0          // 256 blocks x 48 (44 used) moment partials
#define WS_ESUM 12288      // 256
#define WS_ESS  12544      // 256
#define WS_BK   12800      // 128
#define WS_BV   12928      // 128
// ws byte offsets
#define WB_BYTE 53248
#define XT_BYTE 331776     // WB + 278528
#define Y_BYTE  2428928    // XT + 2MB   (total ~4.43MB)
// short offsets inside wb
#define WQB   0
#define WVB   16384
#define WK2B  32768
#define WV2B  49152
#define WEB   65536
#define WK1F  131072
#define WV1F  135168

typedef unsigned short ushort_t;
typedef unsigned int   uint_t;
typedef __attribute__((ext_vector_type(8))) short s8v;
typedef __attribute__((ext_vector_type(4))) short s4v;
typedef __attribute__((ext_vector_type(4))) float f4v;
typedef __bf16 bf16x8 __attribute__((ext_vector_type(8)));

constexpr int   P_TOT  = B_ * N_ * K_;
constexpr float INV_P  = 1.0f / (float)P_TOT;
constexpr float INV_BN = 1.0f / (float)(B_ * N_);

__device__ __forceinline__ float b2f(ushort_t u) {
    return __uint_as_float(((uint_t)u) << 16);
}
__device__ __forceinline__ ushort_t f2b(float f) {
    return __builtin_bit_cast(ushort_t, (__bf16)f);
}
__device__ __forceinline__ bf16x8 ld8(const ushort_t* p) {
    return __builtin_bit_cast(bf16x8, *(const s8v*)p);
}
__device__ __forceinline__ int qx2(int c, int k) {       // v-tile swizzle
    return (c * 32 + k) ^ (((c >> 1) & 7) << 3);
}

// ---------------------------------------------------------------------------
// prep: moments partials (blk<256) | xT bf16 coalesced (256..511) |
//       weights bf16 + ESUM/ESS zero (512..639)
// ---------------------------------------------------------------------------
__global__ __launch_bounds__(256) void prep_kernel(
    const float* __restrict__ x, const float* __restrict__ SiPF,
    const float* __restrict__ w_kv, const float* __restrict__ wk2,
    const float* __restrict__ wv2, const float* __restrict__ we,
    float* __restrict__ ws, ushort_t* __restrict__ wb,
    ushort_t* __restrict__ xT)
{
    __shared__ float red[4][44];
    __shared__ float tile[32][129];
    const int blk = blockIdx.x;
    const int t   = threadIdx.x;

    if (blk < 256) {                                 // ---- moment partials
        float s1[8], s2[36];
#pragma unroll
        for (int i = 0; i < 8; ++i) s1[i] = 0.f;
#pragma unroll
        for (int i = 0; i < 36; ++i) s2[i] = 0.f;
        const int tid = blk * 256 + t;
#pragma unroll
        for (int it = 0; it < P_TOT / 65536; ++it) {
            const float4* base = (const float4*)(SiPF + (size_t)(tid + it * 65536) * 8);
            float4 a = base[0], bq = base[1];
            float v[8] = {a.x, a.y, a.z, a.w, bq.x, bq.y, bq.z, bq.w};
            int idx = 0;
#pragma unroll
            for (int i = 0; i < 8; ++i) {
                s1[i] += v[i];
#pragma unroll
                for (int j = i; j < 8; ++j) s2[idx++] += v[i] * v[j];
            }
        }
#pragma unroll
        for (int i = 0; i < 8; ++i)
            for (int m = 32; m; m >>= 1) s1[i] += __shfl_xor(s1[i], m);
#pragma unroll
        for (int i = 0; i < 36; ++i)
            for (int m = 32; m; m >>= 1) s2[i] += __shfl_xor(s2[i], m);
        if ((t & 63) == 0) {
            const int w = t >> 6;
#pragma unroll
            for (int i = 0; i < 8; ++i) red[w][i] = s1[i];
#pragma unroll
            for (int i = 0; i < 36; ++i) red[w][8 + i] = s2[i];
        }
        __syncthreads();
        if (t < 44)
            ws[WS_MP + blk * 48 + t] = red[0][t] + red[1][t] + red[2][t] + red[3][t];
    } else if (blk < 512) {                          // ---- x -> xT bf16
        const int tb = blk - 256;
        const int b  = tb >> 5;
        const int n0 = (tb & 31) << 5;
        const int cgr = t >> 5, n = t & 31;
#pragma unroll
        for (int i = 0; i < 16; ++i) {
            const int c = cgr * 16 + i;
            tile[n][c] = x[((size_t)(b * CIN + c)) * N_ + n0 + n];
        }
        __syncthreads();
        const int nr = t >> 3, c0 = (t & 7) * 16;
        s8v o0, o1;
#pragma unroll
        for (int j = 0; j < 8; ++j) {
            o0[j] = (short)f2b(tile[nr][c0 + j]);
            o1[j] = (short)f2b(tile[nr][c0 + 8 + j]);
        }
        s8v* dst = (s8v*)(xT + ((size_t)(b * N_ + n0 + nr)) * 128 + c0);
        dst[0] = o0; dst[1] = o1;
    } else {                                         // ---- weights -> bf16
        if (blk == 512) {                            // zero bne accumulators
            ws[WS_ESUM + t] = 0.f;
            ws[WS_ESS + t]  = 0.f;
        }
        const int base = (blk - 512) * 1024 + t;
#pragma unroll
        for (int i = 0; i < 4; ++i) {
            const int e = base + i * 256;
            float v;
            if (e < 32768)      v = w_kv[e];
            else if (e < 49152) v = wk2[e - 32768];
            else if (e < 65536) v = wv2[e - 49152];
            else                v = we[e - 65536];
            wb[e] = f2b(v);
        }
    }
}

// ---------------------------------------------------------------------------
// prep2: reduce moment partials, BN-fold coeffs, folded bf16 wk1/wv1
// ---------------------------------------------------------------------------
__global__ __launch_bounds__(128) void prep2_kernel(
    const float* __restrict__ wk1, const float* __restrict__ wv1,
    const float* __restrict__ bnk_gamma, const float* __restrict__ bnk_beta,
    const float* __restrict__ bnv_gamma, const float* __restrict__ bnv_beta,
    float* __restrict__ ws, ushort_t* __restrict__ wb)
{
    __shared__ float red2[44];
    const int c = threadIdx.x;
    if (c < 44) {
        float s = 0.f;
        for (int bq = 0; bq < 256; ++bq) s += ws[WS_MP + bq * 48 + c];
        red2[c] = s;
    }
    __syncthreads();

    float m1[8], wkr[8], wvr[8];
#pragma unroll
    for (int s = 0; s < 8; ++s) {
        m1[s]  = red2[s] * INV_P;
        wkr[s] = wk1[c * 8 + s];
        wvr[s] = wv1[c * 8 + s];
    }
    float mk = 0.f, mv = 0.f;
#pragma unroll
    for (int s = 0; s < 8; ++s) { mk += wkr[s] * m1[s]; mv += wvr[s] * m1[s]; }
    float ek = 0.f, ev = 0.f;
#pragma unroll
    for (int s = 0; s < 8; ++s)
#pragma unroll
        for (int s2 = 0; s2 < 8; ++s2) {
            const int i = s < s2 ? s : s2;
            const int j = s < s2 ? s2 : s;
            const float m2 = red2[8 + 8 * i - (i * (i - 1)) / 2 + (j - i)] * INV_P;
            ek += wkr[s] * wkr[s2] * m2;
            ev += wvr[s] * wvr[s2] * m2;
        }
    const float Ak = bnk_gamma[c] * rsqrtf(ek - mk * mk + EPSF);
    const float Av = bnv_gamma[c] * rsqrtf(ev - mv * mv + EPSF);
    ws[WS_BK + c] = bnk_beta[c] - mk * Ak;           // bv1 cancels in BN
    ws[WS_BV + c] = bnv_beta[c] - mv * Av;
#pragma unroll
    for (int s = 0; s < 32; ++s) {
        wb[WK1F + c * 32 + s] = s < 8 ? f2b(Ak * wkr[s]) : (ushort_t)0;
        wb[WV1F + c * 32 + s] = s < 8 ? f2b(Av * wvr[s]) : (ushort_t)0;
    }
}

// ---------------------------------------------------------------------------
// main: R10 verbatim — 512 threads / 8 waves, TWO positions per block.
// ---------------------------------------------------------------------------
__global__ __launch_bounds__(512, 4) void main_kernel(
    const float* __restrict__ SiPF, const float* __restrict__ bv2,
    const int* __restrict__ col,    const float* __restrict__ ws,
    const ushort_t* __restrict__ wb, const ushort_t* __restrict__ xT,
    ushort_t* __restrict__ y)
{
    __shared__ __align__(16) ushort_t T1[2][4096];   // fsT [k][c]; then P~
    __shared__ __align__(16) ushort_t T2[2][4096];   // hkT; then qT
    __shared__ __align__(16) ushort_t T3[2][4096];   // hvT; then v [c][k]
    __shared__ __align__(16) ushort_t T4[2][4096];   // sipf head; then kkT

    const int bid = blockIdx.x;                      // 4096 blocks
    const int pi  = (bid & 7) * 512 + (bid >> 3);    // XCD swizzle, bijective
    const int t   = threadIdx.x;

    // ---- Phase A: stage sipf + gather fs for position p = t>>8 ----
    {
        const int p  = t >> 8;
        const int bn = pi * 2 + p;
        const int b  = bn >> 10;
        const int tt = t & 255;
        const int k  = tt & 31;
        const int cg = tt >> 5;
        if (cg < 4) {
            const int slot = (cg * 8) ^ ((k & 3) << 3);
            s8v o8 = {0, 0, 0, 0, 0, 0, 0, 0};
            if (cg == 0) {
                const float4* sp = (const float4*)(SiPF + (size_t)bn * 256 + k * 8);
                const float4 sa = sp[0], sq = sp[1];
                o8[0] = (short)f2b(sa.x); o8[1] = (short)f2b(sa.y);
                o8[2] = (short)f2b(sa.z); o8[3] = (short)f2b(sa.w);
                o8[4] = (short)f2b(sq.x); o8[5] = (short)f2b(sq.y);
                o8[6] = (short)f2b(sq.z); o8[7] = (short)f2b(sq.w);
            }
            *(s8v*)&T4[p][k * 32 + slot] = o8;
        }
        const int idxk = col[bn * K_ + k] - b * N_;
        const s8v* xrow = (const s8v*)(xT + ((size_t)(b << 10) + idxk) * 128 + cg * 16);
        const s8v f0 = xrow[0], f1 = xrow[1];
        const int base = k * 128 + cg * 16;
        const int sw   = (k & 7) << 3;
        *(s8v*)&T1[p][(base) ^ sw]     = f0;
        *(s8v*)&T1[p][(base + 8) ^ sw] = f1;
    }
    __syncthreads();

    const int wv_ = t >> 6, l = t & 63, lr = l & 15, lg = l >> 4;
    const int cw  = wv_ * 16;                        // wave channel stripe
    const f4v z4 = {0.f, 0.f, 0.f, 0.f};

    // ---- Phase A2: hk/hv for both positions (MFMA, K=8 zero-padded) ----
    {
        bf16x8 sb[4];
#pragma unroll
        for (int nt = 0; nt < 4; ++nt) {
            const int pp  = nt >> 1;
            const int row = (nt & 1) * 16 + lr;
            sb[nt] = ld8(&T4[pp][row * 32 + ((lg * 8) ^ ((row & 3) << 3))]);
        }
        const float4 bka = *(const float4*)&ws[WS_BK + cw + lg * 4];
        const float4 bva = *(const float4*)&ws[WS_BV + cw + lg * 4];
        const float Bk_[4] = {bka.x, bka.y, bka.z, bka.w};
        const float Bv_[4] = {bva.x, bva.y, bva.z, bva.w};
        const bf16x8 a1 = ld8(&wb[WK1F + (cw + lr) * 32 + lg * 8]);
        const bf16x8 a2 = ld8(&wb[WV1F + (cw + lr) * 32 + lg * 8]);
        f4v hka[4], hva[4];
#pragma unroll
        for (int nt = 0; nt < 4; ++nt) {
            hka[nt] = __builtin_amdgcn_mfma_f32_16x16x32_bf16(a1, sb[nt], z4, 0, 0, 0);
            hva[nt] = __builtin_amdgcn_mfma_f32_16x16x32_bf16(a2, sb[nt], z4, 0, 0, 0);
        }
#pragma unroll
        for (int nt = 0; nt < 4; ++nt) {
            const int pp  = nt >> 1;
            const int c0  = cw + lg * 4;
            const int kc  = (nt & 1) * 16 + lr;
            const int idx = (kc * 128 + c0) ^ ((kc & 7) << 3);
            s4v hk4, hv4;
#pragma unroll
            for (int r = 0; r < 4; ++r) {
                hk4[r] = (short)f2b(fmaxf(hka[nt][r] + Bk_[r], 0.f));
                hv4[r] = (short)f2b(fmaxf(hva[nt][r] + Bv_[r], 0.f));
            }
            *(s4v*)&T2[pp][idx] = hk4;
            *(s4v*)&T3[pp][idx] = hv4;
        }
    }
    __syncthreads();

    // ---- Phase CB: 4 GEMMs x N=64 (both positions), 64 MFMA/wave ----
    f4v ck[4], cs[4], aq[4], av[4];
#pragma unroll
    for (int nt = 0; nt < 4; ++nt) { ck[nt] = z4; cs[nt] = z4; aq[nt] = z4; av[nt] = z4; }
    __builtin_amdgcn_s_setprio(1);
#pragma unroll
    for (int kt = 0; kt < 4; ++kt) {
        const int cp0 = kt * 32 + lg * 8;
        bf16x8 bk[4], bv[4], bfr[4];
#pragma unroll
        for (int nt = 0; nt < 4; ++nt) {
            const int pp  = nt >> 1;
            const int kk_ = (nt & 1) * 16 + lr;
            const int idx = (kk_ * 128 + cp0) ^ ((lr & 7) << 3);
            bk[nt]  = ld8(&T2[pp][idx]);
            bv[nt]  = ld8(&T3[pp][idx]);
            bfr[nt] = ld8(&T1[pp][idx]);
        }
        const int c = cw + lr;
        const bf16x8 a1 = ld8(&wb[WK2B + c * 128 + cp0]);
        const bf16x8 a2 = ld8(&wb[WV2B + c * 128 + cp0]);
        const bf16x8 a3 = ld8(&wb[WQB  + c * 128 + cp0]);
        const bf16x8 a4 = ld8(&wb[WVB  + c * 128 + cp0]);
#pragma unroll
        for (int nt = 0; nt < 4; ++nt) {
            ck[nt] = __builtin_amdgcn_mfma_f32_16x16x32_bf16(a1, bk[nt],  ck[nt], 0, 0, 0);
            cs[nt] = __builtin_amdgcn_mfma_f32_16x16x32_bf16(a2, bv[nt],  cs[nt], 0, 0, 0);
            aq[nt] = __builtin_amdgcn_mfma_f32_16x16x32_bf16(a3, bfr[nt], aq[nt], 0, 0, 0);
            av[nt] = __builtin_amdgcn_mfma_f32_16x16x32_bf16(a4, bfr[nt], av[nt], 0, 0, 0);
        }
    }
    __builtin_amdgcn_s_setprio(0);
    // kk -> T4 (sipf dead since A2 barrier; disjoint per-wave rows)
#pragma unroll
    for (int nt = 0; nt < 4; ++nt) {
        const int pp  = nt >> 1;
        const int c0  = cw + lg * 4;
        const int kk_ = (nt & 1) * 16 + lr;
        const int idx = (kk_ * 128 + c0) ^ ((kk_ & 7) << 3);
        s4v ck4;
#pragma unroll
        for (int r = 0; r < 4; ++r) ck4[r] = (short)f2b(ck[nt][r]);
        *(s4v*)&T4[pp][idx] = ck4;
    }
    __syncthreads();   // all T1/T2/T3 reads complete

    // ---- q -> T2 (scaled), v = vfs*(cs+bv2) -> T3 ----
    {
        const float4 bvv = *(const float4*)&bv2[cw + lg * 4];
        const float bv2_[4] = {bvv.x, bvv.y, bvv.z, bvv.w};
        const float SC = 0.17677669529663687f;       // 1/sqrt(32)
#pragma unroll
        for (int nt = 0; nt < 4; ++nt) {
            const int pp  = nt >> 1;
            const int c0  = cw + lg * 4;
            const int kk_ = (nt & 1) * 16 + lr;
            const int idx = (kk_ * 128 + c0) ^ ((kk_ & 7) << 3);
            s4v q4;
#pragma unroll
            for (int r = 0; r < 4; ++r) {
                q4[r] = (short)f2b(aq[nt][r] * SC);
                T3[pp][qx2(c0 + r, kk_)] =
                    f2b(av[nt][r] * (cs[nt][r] + bv2_[r]));
            }
            *(s4v*)&T2[pp][idx] = q4;
        }
    }
    __syncthreads();

    // ---- Phase D: attention, wave -> (position, head) ----
    // Shuffle-free softmax (R10-verified): P~=exp(s) unnormalized;
    // rs = mfma(ones, P~) lands at col=kq=lr — lane-aligned with o2 cols.
    {
        const int pp = wv_ >> 2;
        const int h  = wv_ & 3;
        const int bn = pi * 2 + pp;
        bf16x8 aqf[2], bkf[2];
#pragma unroll
        for (int mt = 0; mt < 2; ++mt)
            aqf[mt] = ld8(&T2[pp][((mt * 16 + lr) * 128 + h * 32 + lg * 8) ^ ((lr & 7) << 3)]);
#pragma unroll
        for (int nt = 0; nt < 2; ++nt)
            bkf[nt] = ld8(&T4[pp][((nt * 16 + lr) * 128 + h * 32 + lg * 8) ^ ((lr & 7) << 3)]);
        f4v s[2][2];
#pragma unroll
        for (int mt = 0; mt < 2; ++mt)
#pragma unroll
            for (int nt = 0; nt < 2; ++nt)
                s[mt][nt] = __builtin_amdgcn_mfma_f32_16x16x32_bf16(aqf[mt], bkf[nt], z4, 0, 0, 0);

        // P~ = exp(s), store unnormalized into T1 (fsT dead)
        ushort_t* P = &T1[pp][h * 1024];
#pragma unroll
        for (int mt = 0; mt < 2; ++mt)
#pragma unroll
            for (int nt = 0; nt < 2; ++nt) {
                const int kq0 = mt * 16 + lg * 4;
                const int j   = nt * 16 + lr;
#pragma unroll
                for (int r = 0; r < 4; ++r) {
                    const int kq = kq0 + r;
                    P[(kq * 32 + j) ^ ((kq & 7) << 3)] = f2b(__expf(s[mt][nt][r]));
                }
            }

        bf16x8 af[2], pb[2];
#pragma unroll
        for (int mt2 = 0; mt2 < 2; ++mt2)
            af[mt2] = ld8(&T3[pp][qx2(h * 32 + mt2 * 16 + lr, lg * 8)]);
#pragma unroll
        for (int nt2 = 0; nt2 < 2; ++nt2) {
            const int kq2 = nt2 * 16 + lr;
            pb[nt2] = ld8(&P[(kq2 * 32 + lg * 8) ^ ((lr & 7) << 3)]);
        }
        const s8v one8 = {(short)0x3F80, (short)0x3F80, (short)0x3F80, (short)0x3F80,
                          (short)0x3F80, (short)0x3F80, (short)0x3F80, (short)0x3F80};
        const bf16x8 ones = __builtin_bit_cast(bf16x8, one8);

        f4v o2[2][2], rsf[2];
        __builtin_amdgcn_s_setprio(1);
#pragma unroll
        for (int mt2 = 0; mt2 < 2; ++mt2)
#pragma unroll
            for (int nt2 = 0; nt2 < 2; ++nt2)
                o2[mt2][nt2] = __builtin_amdgcn_mfma_f32_16x16x32_bf16(af[mt2], pb[nt2], z4, 0, 0, 0);
#pragma unroll
        for (int nt2 = 0; nt2 < 2; ++nt2)
            rsf[nt2] = __builtin_amdgcn_mfma_f32_16x16x32_bf16(ones, pb[nt2], z4, 0, 0, 0);
        __builtin_amdgcn_s_setprio(0);

        const float inv0 = 1.0f / rsf[0][0];
        const float inv1 = 1.0f / rsf[1][0];

        float ym[2][4];
#pragma unroll
        for (int mt2 = 0; mt2 < 2; ++mt2)
#pragma unroll
            for (int r = 0; r < 4; ++r)
                ym[mt2][r] = fmaxf(o2[mt2][0][r] * inv0, o2[mt2][1][r] * inv1);
        // butterfly over lr bits only (lg lanes hold different channels)
#pragma unroll
        for (int m = 1; m <= 8; m <<= 1)
#pragma unroll
            for (int mt2 = 0; mt2 < 2; ++mt2)
#pragma unroll
                for (int r = 0; r < 4; ++r)
                    ym[mt2][r] = fmaxf(ym[mt2][r], __shfl_xor(ym[mt2][r], m));
        if (lr == 0) {
#pragma unroll
            for (int mt2 = 0; mt2 < 2; ++mt2) {
                unsigned long long pk = 0;
#pragma unroll
                for (int r = 0; r < 4; ++r)
                    pk |= ((unsigned long long)f2b(ym[mt2][r])) << (16 * r);
                *(unsigned long long*)&y[(size_t)bn * 128 + h * 32 + mt2 * 16 + lg * 4] = pk;
            }
        }
    }
}

// ---------------------------------------------------------------------------
// zgemm (cooperative): z = we_bf16 @ cat(y-x, x); stats atomics ->
// grid.sync() -> normalize accumulators in registers -> out + leaky.
// 1024 blocks x 256 thr (4 waves): 4 blk/CU co-resident (8KB LDS, low VGPR).
// ---------------------------------------------------------------------------
__global__ __launch_bounds__(256, 4) void zgemm_kernel(
    const ushort_t* __restrict__ wb, const ushort_t* __restrict__ xT,
    const ushort_t* __restrict__ y, float* __restrict__ ws,
    const float* __restrict__ gamma, const float* __restrict__ beta,
    float* __restrict__ out)
{
    __shared__ __align__(16) ushort_t Bt[16 * 256];  // [bn-local 16][c] swz
    const int blk = blockIdx.x;                      // 1024 blocks
    const int bn0 = (blk >> 1) * 16;
    const int mh  = (blk & 1) * 128;
    const int t   = threadIdx.x;
    {
        const int r   = t >> 4;                      // 16 rows
        const int c0  = (t & 15) * 16;               // 16 cols of 256
        const int bnr = bn0 + r;
        const int sw  = (r & 7) << 3;
        if (c0 < 128) {                              // (y - x) half
            const s8v y0 = *(const s8v*)(y  + (size_t)bnr * 128 + c0);
            const s8v x0 = *(const s8v*)(xT + (size_t)bnr * 128 + c0);
            const s8v y1 = *(const s8v*)(y  + (size_t)bnr * 128 + c0 + 8);
            const s8v x1 = *(const s8v*)(xT + (size_t)bnr * 128 + c0 + 8);
            s8v d0, d1;
#pragma unroll
            for (int j = 0; j < 8; ++j) {
                d0[j] = (short)f2b(b2f((ushort_t)y0[j]) - b2f((ushort_t)x0[j]));
                d1[j] = (short)f2b(b2f((ushort_t)y1[j]) - b2f((ushort_t)x1[j]));
            }
            *(s8v*)&Bt[(r * 256 + c0) ^ sw]     = d0;
            *(s8v*)&Bt[(r * 256 + c0 + 8) ^ sw] = d1;
        } else {                                     // x half
            const s8v x0 = *(const s8v*)(xT + (size_t)bnr * 128 + (c0 - 128));
            const s8v x1 = *(const s8v*)(xT + (size_t)bnr * 128 + (c0 - 128) + 8);
            *(s8v*)&Bt[(r * 256 + c0) ^ sw]     = x0;
            *(s8v*)&Bt[(r * 256 + c0 + 8) ^ sw] = x1;
        }
    }
    __syncthreads();

    const int w = t >> 6, l = t & 63, lr = l & 15, lg = l >> 4;
    const f4v z4 = {0.f, 0.f, 0.f, 0.f};
    f4v acc[2];
    acc[0] = z4; acc[1] = z4;

#pragma unroll
    for (int kt = 0; kt < 8; ++kt) {
        const int kc = kt * 32 + lg * 8;
        const bf16x8 bf = ld8(&Bt[(lr * 256 + kc) ^ ((lr & 7) << 3)]);
#pragma unroll
        for (int mt = 0; mt < 2; ++mt) {
            const int o = mh + w * 32 + mt * 16 + lr;
            const bf16x8 am = ld8(&wb[WEB + o * 256 + kc]);
            acc[mt] = __builtin_amdgcn_mfma_f32_16x16x32_bf16(am, bf, acc[mt], 0, 0, 0);
        }
    }

    // stats (atomics into ws)
    float sm[2][4], sq[2][4];
#pragma unroll
    for (int mt = 0; mt < 2; ++mt)
#pragma unroll
        for (int r = 0; r < 4; ++r) {
            const float a0 = acc[mt][r];
            sm[mt][r] = a0;
            sq[mt][r] = a0 * a0;
        }
#pragma unroll
    for (int m = 1; m <= 8; m <<= 1)
#pragma unroll
        for (int mt = 0; mt < 2; ++mt)
#pragma unroll
            for (int r = 0; r < 4; ++r) {
                sm[mt][r] += __shfl_xor(sm[mt][r], m);
                sq[mt][r] += __shfl_xor(sq[mt][r], m);
            }
    if (lr == 0) {
#pragma unroll
        for (int mt = 0; mt < 2; ++mt)
#pragma unroll
            for (int r = 0; r < 4; ++r) {
                const int o = mh + w * 32 + mt * 16 + lg * 4 + r;
                atomicAdd(&ws[WS_ESUM + o], sm[mt][r]);
                atomicAdd(&ws[WS_ESS + o],  sq[mt][r]);
            }
    }

    cg::this_grid().sync();                          // all stats complete

    // normalize in registers, apply leaky, single write
    const int b = bn0 >> 10;
#pragma unroll
    for (int mt = 0; mt < 2; ++mt)
#pragma unroll
        for (int r = 0; r < 4; ++r) {
            const int o = mh + w * 32 + mt * 16 + lg * 4 + r;
            const float mean = ws[WS_ESUM + o] * INV_BN;
            const float var  = ws[WS_ESS + o] * INV_BN - mean * mean;
            const float A  = gamma[o] * rsqrtf(var + EPSF);
            const float Bb = beta[o] - mean * A;
            const int n = (bn0 + lr) & (N_ - 1);
            const float rv = A * acc[mt][r] + Bb;
            out[((size_t)(b * COUT + o)) * N_ + n] = rv >= 0.f ? rv : NEG * rv;
        }
}

// ---------------------------------------------------------------------------
extern "C" void kernel_launch(void* const* d_in, const int* in_sizes, int n_in,
                              void* d_out, int out_size, void* d_ws, size_t ws_size,
                              hipStream_t stream)
{
    (void)in_sizes; (void)n_in; (void)out_size; (void)ws_size;

    const float* x         = (const float*)d_in[0];
    const float* SiPF      = (const float*)d_in[1];
    const float* w_kv      = (const float*)d_in[2];
    const float* wk1       = (const float*)d_in[3];
    const float* bnk_gamma = (const float*)d_in[4];
    const float* bnk_beta  = (const float*)d_in[5];
    const float* wk2       = (const float*)d_in[6];
    const float* wv1       = (const float*)d_in[7];
    // d_in[8] = bv1: cancels inside _bn2d — unused
    const float* bnv_gamma = (const float*)d_in[9];
    const float* bnv_beta  = (const float*)d_in[10];
    const float* wv2       = (const float*)d_in[11];
    const float* bv2       = (const float*)d_in[12];
    const float* we        = (const float*)d_in[13];
    const float* bne_gamma = (const float*)d_in[14];
    const float* bne_beta  = (const float*)d_in[15];
    const int*   col       = (const int*)d_in[16];

    float*    ws = (float*)d_ws;
    ushort_t* wb = (ushort_t*)((char*)d_ws + WB_BYTE);
    ushort_t* xT = (ushort_t*)((char*)d_ws + XT_BYTE);
    ushort_t* y  = (ushort_t*)((char*)d_ws + Y_BYTE);
    float*    outp = (float*)d_out;

    prep_kernel<<<640, 256, 0, stream>>>(x, SiPF, w_kv, wk2, wv2, we, ws, wb, xT);
    prep2_kernel<<<1, 128, 0, stream>>>(wk1, wv1, bnk_gamma, bnk_beta,
                                        bnv_gamma, bnv_beta, ws, wb);
    main_kernel<<<4096, 512, 0, stream>>>(SiPF, bv2, col, ws, wb, xT, y);

    void* zargs[] = {(void*)&wb, (void*)&xT, (void*)&y, (void*)&ws,
                     (void*)&bne_gamma, (void*)&bne_beta, (void*)&outp};
    hipLaunchCooperativeKernel((const void*)zgemm_kernel, dim3(1024), dim3(256),
                               zargs, 0, stream);
}

// Round 14
// 178.269 us; speedup vs baseline: 1.6205x; 1.4660x over previous
//
// RINet fused — R14: R10 locked + non-coop 1024-block zgemm + SC folded in Wq
// Journal: R1 3762 | R2 505 | R3 312 | R4 253 | R5 260 spill | R6 243 |
// R7 181.8 | R8 186.9 spill | R9 FAIL | R10 159.1 BEST (main 114) | R11 196
// (gather in CB) | R12 289 (persistent prefetch spilled) | R13 261 (coop
// grid.sync spin = 124us). Main is at the 128-reg cliff (64 VGPR + 64 AGPR
// accums) + 64KB LDS floor: occupancy/pipeline paths closed. R14: (1) zgemm
// non-cooperative at 1024 blocks (16bn x Mhalf; R13's cheap GEMM shape) +
// R10's 5us in-place apply; (2) 1/sqrt(32) pre-folded into bf16 Wq at prep.
#include <hip/hip_runtime.h>

#define B_    8
#define N_    1024
#define K_    32
#define CIN   128
#define COUT  256
#define EPSF  1e-5f
#define NEG   0.2f

// ws float offsets
#define WS_MP   0          // 256 blocks x 48 (44 used) moment partials
#define WS_ESUM 12288      // 256
#define WS_ESS  12544      // 256
#define WS_BK   12800      // 128
#define WS_BV   12928      // 128
// ws byte offsets
#define WB_BYTE 53248
#define XT_BYTE 331776     // WB + 278528
#define Y_BYTE  2428928    // XT + 2MB   (total ~4.43MB)
// short offsets inside wb
#define WQB   0
#define WVB   16384
#define WK2B  32768
#define WV2B  49152
#define WEB   65536
#define WK1F  131072
#define WV1F  135168

typedef unsigned short ushort_t;
typedef unsigned int   uint_t;
typedef __attribute__((ext_vector_type(8))) short s8v;
typedef __attribute__((ext_vector_type(4))) short s4v;
typedef __attribute__((ext_vector_type(4))) float f4v;
typedef __bf16 bf16x8 __attribute__((ext_vector_type(8)));

constexpr int   P_TOT  = B_ * N_ * K_;
constexpr float INV_P  = 1.0f / (float)P_TOT;
constexpr float INV_BN = 1.0f / (float)(B_ * N_);

__device__ __forceinline__ float b2f(ushort_t u) {
    return __uint_as_float(((uint_t)u) << 16);
}
__device__ __forceinline__ ushort_t f2b(float f) {
    return __builtin_bit_cast(ushort_t, (__bf16)f);
}
__device__ __forceinline__ bf16x8 ld8(const ushort_t* p) {
    return __builtin_bit_cast(bf16x8, *(const s8v*)p);
}
__device__ __forceinline__ int qx2(int c, int k) {       // v-tile swizzle
    return (c * 32 + k) ^ (((c >> 1) & 7) << 3);
}

// ---------------------------------------------------------------------------
// prep: moments partials (blk<256) | xT bf16 coalesced (256..511) |
//       weights bf16 (Wq pre-scaled by 1/sqrt(32)) + ESUM/ESS zero (512..639)
// ---------------------------------------------------------------------------
__global__ __launch_bounds__(256) void prep_kernel(
    const float* __restrict__ x, const float* __restrict__ SiPF,
    const float* __restrict__ w_kv, const float* __restrict__ wk2,
    const float* __restrict__ wv2, const float* __restrict__ we,
    float* __restrict__ ws, ushort_t* __restrict__ wb,
    ushort_t* __restrict__ xT)
{
    __shared__ float red[4][44];
    __shared__ float tile[32][129];
    const int blk = blockIdx.x;
    const int t   = threadIdx.x;

    if (blk < 256) {                                 // ---- moment partials
        float s1[8], s2[36];
#pragma unroll
        for (int i = 0; i < 8; ++i) s1[i] = 0.f;
#pragma unroll
        for (int i = 0; i < 36; ++i) s2[i] = 0.f;
        const int tid = blk * 256 + t;
#pragma unroll
        for (int it = 0; it < P_TOT / 65536; ++it) {
            const float4* base = (const float4*)(SiPF + (size_t)(tid + it * 65536) * 8);
            float4 a = base[0], bq = base[1];
            float v[8] = {a.x, a.y, a.z, a.w, bq.x, bq.y, bq.z, bq.w};
            int idx = 0;
#pragma unroll
            for (int i = 0; i < 8; ++i) {
                s1[i] += v[i];
#pragma unroll
                for (int j = i; j < 8; ++j) s2[idx++] += v[i] * v[j];
            }
        }
#pragma unroll
        for (int i = 0; i < 8; ++i)
            for (int m = 32; m; m >>= 1) s1[i] += __shfl_xor(s1[i], m);
#pragma unroll
        for (int i = 0; i < 36; ++i)
            for (int m = 32; m; m >>= 1) s2[i] += __shfl_xor(s2[i], m);
        if ((t & 63) == 0) {
            const int w = t >> 6;
#pragma unroll
            for (int i = 0; i < 8; ++i) red[w][i] = s1[i];
#pragma unroll
            for (int i = 0; i < 36; ++i) red[w][8 + i] = s2[i];
        }
        __syncthreads();
        if (t < 44)
            ws[WS_MP + blk * 48 + t] = red[0][t] + red[1][t] + red[2][t] + red[3][t];
    } else if (blk < 512) {                          // ---- x -> xT bf16
        const int tb = blk - 256;
        const int b  = tb >> 5;
        const int n0 = (tb & 31) << 5;
        const int cgr = t >> 5, n = t & 31;
#pragma unroll
        for (int i = 0; i < 16; ++i) {
            const int c = cgr * 16 + i;
            tile[n][c] = x[((size_t)(b * CIN + c)) * N_ + n0 + n];
        }
        __syncthreads();
        const int nr = t >> 3, c0 = (t & 7) * 16;
        s8v o0, o1;
#pragma unroll
        for (int j = 0; j < 8; ++j) {
            o0[j] = (short)f2b(tile[nr][c0 + j]);
            o1[j] = (short)f2b(tile[nr][c0 + 8 + j]);
        }
        s8v* dst = (s8v*)(xT + ((size_t)(b * N_ + n0 + nr)) * 128 + c0);
        dst[0] = o0; dst[1] = o1;
    } else {                                         // ---- weights -> bf16
        if (blk == 512) {                            // zero bne accumulators
            ws[WS_ESUM + t] = 0.f;
            ws[WS_ESS + t]  = 0.f;
        }
        const float SC = 0.17677669529663687f;       // 1/sqrt(32) -> into Wq
        const int base = (blk - 512) * 1024 + t;
#pragma unroll
        for (int i = 0; i < 4; ++i) {
            const int e = base + i * 256;
            float v;
            if (e < 16384)      v = w_kv[e] * SC;    // Wq rows, pre-scaled
            else if (e < 32768) v = w_kv[e];         // Wv rows
            else if (e < 49152) v = wk2[e - 32768];
            else if (e < 65536) v = wv2[e - 49152];
            else                v = we[e - 65536];
            wb[e] = f2b(v);
        }
    }
}

// ---------------------------------------------------------------------------
// prep2: reduce moment partials, BN-fold coeffs, folded bf16 wk1/wv1
// ---------------------------------------------------------------------------
__global__ __launch_bounds__(128) void prep2_kernel(
    const float* __restrict__ wk1, const float* __restrict__ wv1,
    const float* __restrict__ bnk_gamma, const float* __restrict__ bnk_beta,
    const float* __restrict__ bnv_gamma, const float* __restrict__ bnv_beta,
    float* __restrict__ ws, ushort_t* __restrict__ wb)
{
    __shared__ float red2[44];
    const int c = threadIdx.x;
    if (c < 44) {
        float s = 0.f;
        for (int bq = 0; bq < 256; ++bq) s += ws[WS_MP + bq * 48 + c];
        red2[c] = s;
    }
    __syncthreads();

    float m1[8], wkr[8], wvr[8];
#pragma unroll
    for (int s = 0; s < 8; ++s) {
        m1[s]  = red2[s] * INV_P;
        wkr[s] = wk1[c * 8 + s];
        wvr[s] = wv1[c * 8 + s];
    }
    float mk = 0.f, mv = 0.f;
#pragma unroll
    for (int s = 0; s < 8; ++s) { mk += wkr[s] * m1[s]; mv += wvr[s] * m1[s]; }
    float ek = 0.f, ev = 0.f;
#pragma unroll
    for (int s = 0; s < 8; ++s)
#pragma unroll
        for (int s2 = 0; s2 < 8; ++s2) {
            const int i = s < s2 ? s : s2;
            const int j = s < s2 ? s2 : s;
            const float m2 = red2[8 + 8 * i - (i * (i - 1)) / 2 + (j - i)] * INV_P;
            ek += wkr[s] * wkr[s2] * m2;
            ev += wvr[s] * wvr[s2] * m2;
        }
    const float Ak = bnk_gamma[c] * rsqrtf(ek - mk * mk + EPSF);
    const float Av = bnv_gamma[c] * rsqrtf(ev - mv * mv + EPSF);
    ws[WS_BK + c] = bnk_beta[c] - mk * Ak;           // bv1 cancels in BN
    ws[WS_BV + c] = bnv_beta[c] - mv * Av;
#pragma unroll
    for (int s = 0; s < 32; ++s) {
        wb[WK1F + c * 32 + s] = s < 8 ? f2b(Ak * wkr[s]) : (ushort_t)0;
        wb[WV1F + c * 32 + s] = s < 8 ? f2b(Av * wvr[s]) : (ushort_t)0;
    }
}

// ---------------------------------------------------------------------------
// main: R10 verbatim (SC now folded into WQB) — 512 thr / 8 waves, 2 pos.
// ---------------------------------------------------------------------------
__global__ __launch_bounds__(512, 4) void main_kernel(
    const float* __restrict__ SiPF, const float* __restrict__ bv2,
    const int* __restrict__ col,    const float* __restrict__ ws,
    const ushort_t* __restrict__ wb, const ushort_t* __restrict__ xT,
    ushort_t* __restrict__ y)
{
    __shared__ __align__(16) ushort_t T1[2][4096];   // fsT [k][c]; then P~
    __shared__ __align__(16) ushort_t T2[2][4096];   // hkT; then qT
    __shared__ __align__(16) ushort_t T3[2][4096];   // hvT; then v [c][k]
    __shared__ __align__(16) ushort_t T4[2][4096];   // sipf head; then kkT

    const int bid = blockIdx.x;                      // 4096 blocks
    const int pi  = (bid & 7) * 512 + (bid >> 3);    // XCD swizzle, bijective
    const int t   = threadIdx.x;

    // ---- Phase A: stage sipf + gather fs for position p = t>>8 ----
    {
        const int p  = t >> 8;
        const int bn = pi * 2 + p;
        const int b  = bn >> 10;
        const int tt = t & 255;
        const int k  = tt & 31;
        const int cg = tt >> 5;
        if (cg < 4) {
            const int slot = (cg * 8) ^ ((k & 3) << 3);
            s8v o8 = {0, 0, 0, 0, 0, 0, 0, 0};
            if (cg == 0) {
                const float4* sp = (const float4*)(SiPF + (size_t)bn * 256 + k * 8);
                const float4 sa = sp[0], sq = sp[1];
                o8[0] = (short)f2b(sa.x); o8[1] = (short)f2b(sa.y);
                o8[2] = (short)f2b(sa.z); o8[3] = (short)f2b(sa.w);
                o8[4] = (short)f2b(sq.x); o8[5] = (short)f2b(sq.y);
                o8[6] = (short)f2b(sq.z); o8[7] = (short)f2b(sq.w);
            }
            *(s8v*)&T4[p][k * 32 + slot] = o8;
        }
        const int idxk = col[bn * K_ + k] - b * N_;
        const s8v* xrow = (const s8v*)(xT + ((size_t)(b << 10) + idxk) * 128 + cg * 16);
        const s8v f0 = xrow[0], f1 = xrow[1];
        const int base = k * 128 + cg * 16;
        const int sw   = (k & 7) << 3;
        *(s8v*)&T1[p][(base) ^ sw]     = f0;
        *(s8v*)&T1[p][(base + 8) ^ sw] = f1;
    }
    __syncthreads();

    const int wv_ = t >> 6, l = t & 63, lr = l & 15, lg = l >> 4;
    const int cw  = wv_ * 16;                        // wave channel stripe
    const f4v z4 = {0.f, 0.f, 0.f, 0.f};

    // ---- Phase A2: hk/hv for both positions (MFMA, K=8 zero-padded) ----
    {
        bf16x8 sb[4];
#pragma unroll
        for (int nt = 0; nt < 4; ++nt) {
            const int pp  = nt >> 1;
            const int row = (nt & 1) * 16 + lr;
            sb[nt] = ld8(&T4[pp][row * 32 + ((lg * 8) ^ ((row & 3) << 3))]);
        }
        const float4 bka = *(const float4*)&ws[WS_BK + cw + lg * 4];
        const float4 bva = *(const float4*)&ws[WS_BV + cw + lg * 4];
        const float Bk_[4] = {bka.x, bka.y, bka.z, bka.w};
        const float Bv_[4] = {bva.x, bva.y, bva.z, bva.w};
        const bf16x8 a1 = ld8(&wb[WK1F + (cw + lr) * 32 + lg * 8]);
        const bf16x8 a2 = ld8(&wb[WV1F + (cw + lr) * 32 + lg * 8]);
        f4v hka[4], hva[4];
#pragma unroll
        for (int nt = 0; nt < 4; ++nt) {
            hka[nt] = __builtin_amdgcn_mfma_f32_16x16x32_bf16(a1, sb[nt], z4, 0, 0, 0);
            hva[nt] = __builtin_amdgcn_mfma_f32_16x16x32_bf16(a2, sb[nt], z4, 0, 0, 0);
        }
#pragma unroll
        for (int nt = 0; nt < 4; ++nt) {
            const int pp  = nt >> 1;
            const int c0  = cw + lg * 4;
            const int kc  = (nt & 1) * 16 + lr;
            const int idx = (kc * 128 + c0) ^ ((kc & 7) << 3);
            s4v hk4, hv4;
#pragma unroll
            for (int r = 0; r < 4; ++r) {
                hk4[r] = (short)f2b(fmaxf(hka[nt][r] + Bk_[r], 0.f));
                hv4[r] = (short)f2b(fmaxf(hva[nt][r] + Bv_[r], 0.f));
            }
            *(s4v*)&T2[pp][idx] = hk4;
            *(s4v*)&T3[pp][idx] = hv4;
        }
    }
    __syncthreads();

    // ---- Phase CB: 4 GEMMs x N=64 (both positions), 64 MFMA/wave ----
    f4v ck[4], cs[4], aq[4], av[4];
#pragma unroll
    for (int nt = 0; nt < 4; ++nt) { ck[nt] = z4; cs[nt] = z4; aq[nt] = z4; av[nt] = z4; }
    __builtin_amdgcn_s_setprio(1);
#pragma unroll
    for (int kt = 0; kt < 4; ++kt) {
        const int cp0 = kt * 32 + lg * 8;
        bf16x8 bk[4], bv[4], bfr[4];
#pragma unroll
        for (int nt = 0; nt < 4; ++nt) {
            const int pp  = nt >> 1;
            const int kk_ = (nt & 1) * 16 + lr;
            const int idx = (kk_ * 128 + cp0) ^ ((lr & 7) << 3);
            bk[nt]  = ld8(&T2[pp][idx]);
            bv[nt]  = ld8(&T3[pp][idx]);
            bfr[nt] = ld8(&T1[pp][idx]);
        }
        const int c = cw + lr;
        const bf16x8 a1 = ld8(&wb[WK2B + c * 128 + cp0]);
        const bf16x8 a2 = ld8(&wb[WV2B + c * 128 + cp0]);
        const bf16x8 a3 = ld8(&wb[WQB  + c * 128 + cp0]);
        const bf16x8 a4 = ld8(&wb[WVB  + c * 128 + cp0]);
#pragma unroll
        for (int nt = 0; nt < 4; ++nt) {
            ck[nt] = __builtin_amdgcn_mfma_f32_16x16x32_bf16(a1, bk[nt],  ck[nt], 0, 0, 0);
            cs[nt] = __builtin_amdgcn_mfma_f32_16x16x32_bf16(a2, bv[nt],  cs[nt], 0, 0, 0);
            aq[nt] = __builtin_amdgcn_mfma_f32_16x16x32_bf16(a3, bfr[nt], aq[nt], 0, 0, 0);
            av[nt] = __builtin_amdgcn_mfma_f32_16x16x32_bf16(a4, bfr[nt], av[nt], 0, 0, 0);
        }
    }
    __builtin_amdgcn_s_setprio(0);
    // kk -> T4 (sipf dead since A2 barrier; disjoint per-wave rows)
#pragma unroll
    for (int nt = 0; nt < 4; ++nt) {
        const int pp  = nt >> 1;
        const int c0  = cw + lg * 4;
        const int kk_ = (nt & 1) * 16 + lr;
        const int idx = (kk_ * 128 + c0) ^ ((kk_ & 7) << 3);
        s4v ck4;
#pragma unroll
        for (int r = 0; r < 4; ++r) ck4[r] = (short)f2b(ck[nt][r]);
        *(s4v*)&T4[pp][idx] = ck4;
    }
    __syncthreads();   // all T1/T2/T3 reads complete

    // ---- q -> T2 (scale pre-folded), v = vfs*(cs+bv2) -> T3 ----
    {
        const float4 bvv = *(const float4*)&bv2[cw + lg * 4];
        const float bv2_[4] = {bvv.x, bvv.y, bvv.z, bvv.w};
#pragma unroll
        for (int nt = 0; nt < 4; ++nt) {
            const int pp  = nt >> 1;
            const int c0  = cw + lg * 4;
            const int kk_ = (nt & 1) * 16 + lr;
            const int idx = (kk_ * 128 + c0) ^ ((kk_ & 7) << 3);
            s4v q4;
#pragma unroll
            for (int r = 0; r < 4; ++r) {
                q4[r] = (short)f2b(aq[nt][r]);
                T3[pp][qx2(c0 + r, kk_)] =
                    f2b(av[nt][r] * (cs[nt][r] + bv2_[r]));
            }
            *(s4v*)&T2[pp][idx] = q4;
        }
    }
    __syncthreads();

    // ---- Phase D: attention, wave -> (position, head) ----
    // Shuffle-free softmax (R10-verified): P~=exp(s) unnormalized;
    // rs = mfma(ones, P~) lands at col=kq=lr — lane-aligned with o2 cols.
    {
        const int pp = wv_ >> 2;
        const int h  = wv_ & 3;
        const int bn = pi * 2 + pp;
        bf16x8 aqf[2], bkf[2];
#pragma unroll
        for (int mt = 0; mt < 2; ++mt)
            aqf[mt] = ld8(&T2[pp][((mt * 16 + lr) * 128 + h * 32 + lg * 8) ^ ((lr & 7) << 3)]);
#pragma unroll
        for (int nt = 0; nt < 2; ++nt)
            bkf[nt] = ld8(&T4[pp][((nt * 16 + lr) * 128 + h * 32 + lg * 8) ^ ((lr & 7) << 3)]);
        f4v s[2][2];
#pragma unroll
        for (int mt = 0; mt < 2; ++mt)
#pragma unroll
            for (int nt = 0; nt < 2; ++nt)
                s[mt][nt] = __builtin_amdgcn_mfma_f32_16x16x32_bf16(aqf[mt], bkf[nt], z4, 0, 0, 0);

        // P~ = exp(s), store unnormalized into T1 (fsT dead)
        ushort_t* P = &T1[pp][h * 1024];
#pragma unroll
        for (int mt = 0; mt < 2; ++mt)
#pragma unroll
            for (int nt = 0; nt < 2; ++nt) {
                const int kq0 = mt * 16 + lg * 4;
                const int j   = nt * 16 + lr;
#pragma unroll
                for (int r = 0; r < 4; ++r) {
                    const int kq = kq0 + r;
                    P[(kq * 32 + j) ^ ((kq & 7) << 3)] = f2b(__expf(s[mt][nt][r]));
                }
            }

        bf16x8 af[2], pb[2];
#pragma unroll
        for (int mt2 = 0; mt2 < 2; ++mt2)
            af[mt2] = ld8(&T3[pp][qx2(h * 32 + mt2 * 16 + lr, lg * 8)]);
#pragma unroll
        for (int nt2 = 0; nt2 < 2; ++nt2) {
            const int kq2 = nt2 * 16 + lr;
            pb[nt2] = ld8(&P[(kq2 * 32 + lg * 8) ^ ((lr & 7) << 3)]);
        }
        const s8v one8 = {(short)0x3F80, (short)0x3F80, (short)0x3F80, (short)0x3F80,
                          (short)0x3F80, (short)0x3F80, (short)0x3F80, (short)0x3F80};
        const bf16x8 ones = __builtin_bit_cast(bf16x8, one8);

        f4v o2[2][2], rsf[2];
        __builtin_amdgcn_s_setprio(1);
#pragma unroll
        for (int mt2 = 0; mt2 < 2; ++mt2)
#pragma unroll
            for (int nt2 = 0; nt2 < 2; ++nt2)
                o2[mt2][nt2] = __builtin_amdgcn_mfma_f32_16x16x32_bf16(af[mt2], pb[nt2], z4, 0, 0, 0);
#pragma unroll
        for (int nt2 = 0; nt2 < 2; ++nt2)
            rsf[nt2] = __builtin_amdgcn_mfma_f32_16x16x32_bf16(ones, pb[nt2], z4, 0, 0, 0);
        __builtin_amdgcn_s_setprio(0);

        const float inv0 = 1.0f / rsf[0][0];
        const float inv1 = 1.0f / rsf[1][0];

        float ym[2][4];
#pragma unroll
        for (int mt2 = 0; mt2 < 2; ++mt2)
#pragma unroll
            for (int r = 0; r < 4; ++r)
                ym[mt2][r] = fmaxf(o2[mt2][0][r] * inv0, o2[mt2][1][r] * inv1);
        // butterfly over lr bits only (lg lanes hold different channels)
#pragma unroll
        for (int m = 1; m <= 8; m <<= 1)
#pragma unroll
            for (int mt2 = 0; mt2 < 2; ++mt2)
#pragma unroll
                for (int r = 0; r < 4; ++r)
                    ym[mt2][r] = fmaxf(ym[mt2][r], __shfl_xor(ym[mt2][r], m));
        if (lr == 0) {
#pragma unroll
            for (int mt2 = 0; mt2 < 2; ++mt2) {
                unsigned long long pk = 0;
#pragma unroll
                for (int r = 0; r < 4; ++r)
                    pk |= ((unsigned long long)f2b(ym[mt2][r])) << (16 * r);
                *(unsigned long long*)&y[(size_t)bn * 128 + h * 32 + mt2 * 16 + lg * 4] = pk;
            }
        }
    }
}

// ---------------------------------------------------------------------------
// zgemm: 1024 blocks (16 bn-rows x M-half); raw z -> d_out + bne stats.
// ---------------------------------------------------------------------------
__global__ __launch_bounds__(256) void zgemm_kernel(
    const ushort_t* __restrict__ wb, const ushort_t* __restrict__ xT,
    const ushort_t* __restrict__ y, float* __restrict__ ws,
    float* __restrict__ out)
{
    __shared__ __align__(16) ushort_t Bt[16 * 256];  // [bn-local 16][c] swz
    const int blk = blockIdx.x;                      // 1024 blocks
    const int bn0 = (blk >> 1) * 16;
    const int mh  = (blk & 1) * 128;
    const int t   = threadIdx.x;
    {
        const int r   = t >> 4;                      // 16 rows
        const int c0  = (t & 15) * 16;               // 16 cols of 256
        const int bnr = bn0 + r;
        const int sw  = (r & 7) << 3;
        if (c0 < 128) {                              // (y - x) half
            const s8v y0 = *(const s8v*)(y  + (size_t)bnr * 128 + c0);
            const s8v x0 = *(const s8v*)(xT + (size_t)bnr * 128 + c0);
            const s8v y1 = *(const s8v*)(y  + (size_t)bnr * 128 + c0 + 8);
            const s8v x1 = *(const s8v*)(xT + (size_t)bnr * 128 + c0 + 8);
            s8v d0, d1;
#pragma unroll
            for (int j = 0; j < 8; ++j) {
                d0[j] = (short)f2b(b2f((ushort_t)y0[j]) - b2f((ushort_t)x0[j]));
                d1[j] = (short)f2b(b2f((ushort_t)y1[j]) - b2f((ushort_t)x1[j]));
            }
            *(s8v*)&Bt[(r * 256 + c0) ^ sw]     = d0;
            *(s8v*)&Bt[(r * 256 + c0 + 8) ^ sw] = d1;
        } else {                                     // x half
            const s8v x0 = *(const s8v*)(xT + (size_t)bnr * 128 + (c0 - 128));
            const s8v x1 = *(const s8v*)(xT + (size_t)bnr * 128 + (c0 - 128) + 8);
            *(s8v*)&Bt[(r * 256 + c0) ^ sw]     = x0;
            *(s8v*)&Bt[(r * 256 + c0 + 8) ^ sw] = x1;
        }
    }
    __syncthreads();

    const int w = t >> 6, l = t & 63, lr = l & 15, lg = l >> 4;
    const f4v z4 = {0.f, 0.f, 0.f, 0.f};
    f4v acc[2];
    acc[0] = z4; acc[1] = z4;

#pragma unroll
    for (int kt = 0; kt < 8; ++kt) {
        const int kc = kt * 32 + lg * 8;
        const bf16x8 bf = ld8(&Bt[(lr * 256 + kc) ^ ((lr & 7) << 3)]);
#pragma unroll
        for (int mt = 0; mt < 2; ++mt) {
            const int o = mh + w * 32 + mt * 16 + lr;
            const bf16x8 am = ld8(&wb[WEB + o * 256 + kc]);
            acc[mt] = __builtin_amdgcn_mfma_f32_16x16x32_bf16(am, bf, acc[mt], 0, 0, 0);
        }
    }

    // stats
    float sm[2][4], sq[2][4];
#pragma unroll
    for (int mt = 0; mt < 2; ++mt)
#pragma unroll
        for (int r = 0; r < 4; ++r) {
            const float a0 = acc[mt][r];
            sm[mt][r] = a0;
            sq[mt][r] = a0 * a0;
        }
#pragma unroll
    for (int m = 1; m <= 8; m <<= 1)
#pragma unroll
        for (int mt = 0; mt < 2; ++mt)
#pragma unroll
            for (int r = 0; r < 4; ++r) {
                sm[mt][r] += __shfl_xor(sm[mt][r], m);
                sq[mt][r] += __shfl_xor(sq[mt][r], m);
            }
    if (lr == 0) {
#pragma unroll
        for (int mt = 0; mt < 2; ++mt)
#pragma unroll
            for (int r = 0; r < 4; ++r) {
                const int o = mh + w * 32 + mt * 16 + lg * 4 + r;
                atomicAdd(&ws[WS_ESUM + o], sm[mt][r]);
                atomicAdd(&ws[WS_ESS + o],  sq[mt][r]);
            }
    }
    // raw z -> out (final layout); apply_kernel normalizes in place
    const int b = bn0 >> 10;
#pragma unroll
    for (int mt = 0; mt < 2; ++mt)
#pragma unroll
        for (int r = 0; r < 4; ++r) {
            const int o = mh + w * 32 + mt * 16 + lg * 4 + r;
            const int n = (bn0 + lr) & (N_ - 1);
            out[((size_t)(b * COUT + o)) * N_ + n] = acc[mt][r];
        }
}

// ---------------------------------------------------------------------------
// apply: in-place BN1d affine + leaky on d_out.
// ---------------------------------------------------------------------------
__global__ __launch_bounds__(256) void apply_kernel(
    const float* __restrict__ ws, const float* __restrict__ gamma,
    const float* __restrict__ beta, float* __restrict__ out)
{
    const int bo = blockIdx.x;                       // (b, o)
    const int o  = bo & 255;
    const int b  = bo >> 8;
    const float mean = ws[WS_ESUM + o] * INV_BN;
    const float var  = ws[WS_ESS + o] * INV_BN - mean * mean;
    const float A  = gamma[o] * rsqrtf(var + EPSF);
    const float Bb = beta[o] - mean * A;
    float4* p = (float4*)(out + ((size_t)(b * COUT + o)) * N_);
    float4 v = p[threadIdx.x];
    float r0 = A * v.x + Bb, r1 = A * v.y + Bb;
    float r2 = A * v.z + Bb, r3 = A * v.w + Bb;
    v.x = r0 >= 0.f ? r0 : NEG * r0;
    v.y = r1 >= 0.f ? r1 : NEG * r1;
    v.z = r2 >= 0.f ? r2 : NEG * r2;
    v.w = r3 >= 0.f ? r3 : NEG * r3;
    p[threadIdx.x] = v;
}

// ---------------------------------------------------------------------------
extern "C" void kernel_launch(void* const* d_in, const int* in_sizes, int n_in,
                              void* d_out, int out_size, void* d_ws, size_t ws_size,
                              hipStream_t stream)
{
    (void)in_sizes; (void)n_in; (void)out_size; (void)ws_size;

    const float* x         = (const float*)d_in[0];
    const float* SiPF      = (const float*)d_in[1];
    const float* w_kv      = (const float*)d_in[2];
    const float* wk1       = (const float*)d_in[3];
    const float* bnk_gamma = (const float*)d_in[4];
    const float* bnk_beta  = (const float*)d_in[5];
    const float* wk2       = (const float*)d_in[6];
    const float* wv1       = (const float*)d_in[7];
    // d_in[8] = bv1: cancels inside _bn2d — unused
    const float* bnv_gamma = (const float*)d_in[9];
    const float* bnv_beta  = (const float*)d_in[10];
    const float* wv2       = (const float*)d_in[11];
    const float* bv2       = (const float*)d_in[12];
    const float* we        = (const float*)d_in[13];
    const float* bne_gamma = (const float*)d_in[14];
    const float* bne_beta  = (const float*)d_in[15];
    const int*   col       = (const int*)d_in[16];

    float*    ws = (float*)d_ws;
    ushort_t* wb = (ushort_t*)((char*)d_ws + WB_BYTE);
    ushort_t* xT = (ushort_t*)((char*)d_ws + XT_BYTE);
    ushort_t* y  = (ushort_t*)((char*)d_ws + Y_BYTE);

    prep_kernel<<<640, 256, 0, stream>>>(x, SiPF, w_kv, wk2, wv2, we, ws, wb, xT);
    prep2_kernel<<<1, 128, 0, stream>>>(wk1, wv1, bnk_gamma, bnk_beta,
                                        bnv_gamma, bnv_beta, ws, wb);
    main_kernel<<<4096, 512, 0, stream>>>(SiPF, bv2, col, ws, wb, xT, y);
    zgemm_kernel<<<1024, 256, 0, stream>>>(wb, xT, y, ws, (float*)d_out);
    apply_kernel<<<2048, 256, 0, stream>>>(ws, bne_gamma, bne_beta,
                                           (float*)d_out);
}

// Round 15
// 153.535 us; speedup vs baseline: 1.8815x; 1.1611x over previous
//
// RINet fused — R15: best-of recombination: R14 main (SC-folded, 108us) +
// R10 zgemm (512 blocks, 32-row tiles — R14's 1024-blk halved-rows doubled
// weight re-reads + atomics: non-main 45->70us).
// Journal: R1 3762 | R2 505 | R3 312 | R4 253 | R5 260 spill | R6 243 |
// R7 181.8 | R8 186.9 spill | R9 FAIL | R10 159.1 | R11 196 | R12 289 |
// R13 261 coop-sync | R14 178.3 (main 108 GOOD, zgemm split BAD).
// Main pinned at 128-reg cliff (64 VGPR + 64 AGPR) + 64KB LDS: structural.
#include <hip/hip_runtime.h>

#define B_    8
#define N_    1024
#define K_    32
#define CIN   128
#define COUT  256
#define EPSF  1e-5f
#define NEG   0.2f

// ws float offsets
#define WS_MP   0          // 256 blocks x 48 (44 used) moment partials
#define WS_ESUM 12288      // 256
#define WS_ESS  12544      // 256
#define WS_BK   12800      // 128
#define WS_BV   12928      // 128
// ws byte offsets
#define WB_BYTE 53248
#define XT_BYTE 331776     // WB + 278528
#define Y_BYTE  2428928    // XT + 2MB   (total ~4.43MB)
// short offsets inside wb
#define WQB   0
#define WVB   16384
#define WK2B  32768
#define WV2B  49152
#define WEB   65536
#define WK1F  131072
#define WV1F  135168

typedef unsigned short ushort_t;
typedef unsigned int   uint_t;
typedef __attribute__((ext_vector_type(8))) short s8v;
typedef __attribute__((ext_vector_type(4))) short s4v;
typedef __attribute__((ext_vector_type(4))) float f4v;
typedef __bf16 bf16x8 __attribute__((ext_vector_type(8)));

constexpr int   P_TOT  = B_ * N_ * K_;
constexpr float INV_P  = 1.0f / (float)P_TOT;
constexpr float INV_BN = 1.0f / (float)(B_ * N_);

__device__ __forceinline__ float b2f(ushort_t u) {
    return __uint_as_float(((uint_t)u) << 16);
}
__device__ __forceinline__ ushort_t f2b(float f) {
    return __builtin_bit_cast(ushort_t, (__bf16)f);
}
__device__ __forceinline__ bf16x8 ld8(const ushort_t* p) {
    return __builtin_bit_cast(bf16x8, *(const s8v*)p);
}
__device__ __forceinline__ int qx2(int c, int k) {       // v-tile swizzle
    return (c * 32 + k) ^ (((c >> 1) & 7) << 3);
}

// ---------------------------------------------------------------------------
// prep: moments partials (blk<256) | xT bf16 coalesced (256..511) |
//       weights bf16 (Wq pre-scaled by 1/sqrt(32)) + ESUM/ESS zero (512..639)
// ---------------------------------------------------------------------------
__global__ __launch_bounds__(256) void prep_kernel(
    const float* __restrict__ x, const float* __restrict__ SiPF,
    const float* __restrict__ w_kv, const float* __restrict__ wk2,
    const float* __restrict__ wv2, const float* __restrict__ we,
    float* __restrict__ ws, ushort_t* __restrict__ wb,
    ushort_t* __restrict__ xT)
{
    __shared__ float red[4][44];
    __shared__ float tile[32][129];
    const int blk = blockIdx.x;
    const int t   = threadIdx.x;

    if (blk < 256) {                                 // ---- moment partials
        float s1[8], s2[36];
#pragma unroll
        for (int i = 0; i < 8; ++i) s1[i] = 0.f;
#pragma unroll
        for (int i = 0; i < 36; ++i) s2[i] = 0.f;
        const int tid = blk * 256 + t;
#pragma unroll
        for (int it = 0; it < P_TOT / 65536; ++it) {
            const float4* base = (const float4*)(SiPF + (size_t)(tid + it * 65536) * 8);
            float4 a = base[0], bq = base[1];
            float v[8] = {a.x, a.y, a.z, a.w, bq.x, bq.y, bq.z, bq.w};
            int idx = 0;
#pragma unroll
            for (int i = 0; i < 8; ++i) {
                s1[i] += v[i];
#pragma unroll
                for (int j = i; j < 8; ++j) s2[idx++] += v[i] * v[j];
            }
        }
#pragma unroll
        for (int i = 0; i < 8; ++i)
            for (int m = 32; m; m >>= 1) s1[i] += __shfl_xor(s1[i], m);
#pragma unroll
        for (int i = 0; i < 36; ++i)
            for (int m = 32; m; m >>= 1) s2[i] += __shfl_xor(s2[i], m);
        if ((t & 63) == 0) {
            const int w = t >> 6;
#pragma unroll
            for (int i = 0; i < 8; ++i) red[w][i] = s1[i];
#pragma unroll
            for (int i = 0; i < 36; ++i) red[w][8 + i] = s2[i];
        }
        __syncthreads();
        if (t < 44)
            ws[WS_MP + blk * 48 + t] = red[0][t] + red[1][t] + red[2][t] + red[3][t];
    } else if (blk < 512) {                          // ---- x -> xT bf16
        const int tb = blk - 256;
        const int b  = tb >> 5;
        const int n0 = (tb & 31) << 5;
        const int cgr = t >> 5, n = t & 31;
#pragma unroll
        for (int i = 0; i < 16; ++i) {
            const int c = cgr * 16 + i;
            tile[n][c] = x[((size_t)(b * CIN + c)) * N_ + n0 + n];
        }
        __syncthreads();
        const int nr = t >> 3, c0 = (t & 7) * 16;
        s8v o0, o1;
#pragma unroll
        for (int j = 0; j < 8; ++j) {
            o0[j] = (short)f2b(tile[nr][c0 + j]);
            o1[j] = (short)f2b(tile[nr][c0 + 8 + j]);
        }
        s8v* dst = (s8v*)(xT + ((size_t)(b * N_ + n0 + nr)) * 128 + c0);
        dst[0] = o0; dst[1] = o1;
    } else {                                         // ---- weights -> bf16
        if (blk == 512) {                            // zero bne accumulators
            ws[WS_ESUM + t] = 0.f;
            ws[WS_ESS + t]  = 0.f;
        }
        const float SC = 0.17677669529663687f;       // 1/sqrt(32) -> into Wq
        const int base = (blk - 512) * 1024 + t;
#pragma unroll
        for (int i = 0; i < 4; ++i) {
            const int e = base + i * 256;
            float v;
            if (e < 16384)      v = w_kv[e] * SC;    // Wq rows, pre-scaled
            else if (e < 32768) v = w_kv[e];         // Wv rows
            else if (e < 49152) v = wk2[e - 32768];
            else if (e < 65536) v = wv2[e - 49152];
            else                v = we[e - 65536];
            wb[e] = f2b(v);
        }
    }
}

// ---------------------------------------------------------------------------
// prep2: reduce moment partials, BN-fold coeffs, folded bf16 wk1/wv1
// ---------------------------------------------------------------------------
__global__ __launch_bounds__(128) void prep2_kernel(
    const float* __restrict__ wk1, const float* __restrict__ wv1,
    const float* __restrict__ bnk_gamma, const float* __restrict__ bnk_beta,
    const float* __restrict__ bnv_gamma, const float* __restrict__ bnv_beta,
    float* __restrict__ ws, ushort_t* __restrict__ wb)
{
    __shared__ float red2[44];
    const int c = threadIdx.x;
    if (c < 44) {
        float s = 0.f;
        for (int bq = 0; bq < 256; ++bq) s += ws[WS_MP + bq * 48 + c];
        red2[c] = s;
    }
    __syncthreads();

    float m1[8], wkr[8], wvr[8];
#pragma unroll
    for (int s = 0; s < 8; ++s) {
        m1[s]  = red2[s] * INV_P;
        wkr[s] = wk1[c * 8 + s];
        wvr[s] = wv1[c * 8 + s];
    }
    float mk = 0.f, mv = 0.f;
#pragma unroll
    for (int s = 0; s < 8; ++s) { mk += wkr[s] * m1[s]; mv += wvr[s] * m1[s]; }
    float ek = 0.f, ev = 0.f;
#pragma unroll
    for (int s = 0; s < 8; ++s)
#pragma unroll
        for (int s2 = 0; s2 < 8; ++s2) {
            const int i = s < s2 ? s : s2;
            const int j = s < s2 ? s2 : s;
            const float m2 = red2[8 + 8 * i - (i * (i - 1)) / 2 + (j - i)] * INV_P;
            ek += wkr[s] * wkr[s2] * m2;
            ev += wvr[s] * wvr[s2] * m2;
        }
    const float Ak = bnk_gamma[c] * rsqrtf(ek - mk * mk + EPSF);
    const float Av = bnv_gamma[c] * rsqrtf(ev - mv * mv + EPSF);
    ws[WS_BK + c] = bnk_beta[c] - mk * Ak;           // bv1 cancels in BN
    ws[WS_BV + c] = bnv_beta[c] - mv * Av;
#pragma unroll
    for (int s = 0; s < 32; ++s) {
        wb[WK1F + c * 32 + s] = s < 8 ? f2b(Ak * wkr[s]) : (ushort_t)0;
        wb[WV1F + c * 32 + s] = s < 8 ? f2b(Av * wvr[s]) : (ushort_t)0;
    }
}

// ---------------------------------------------------------------------------
// main: R14 verbatim (SC folded into WQB) — 512 thr / 8 waves, 2 pos/block.
// ---------------------------------------------------------------------------
__global__ __launch_bounds__(512, 4) void main_kernel(
    const float* __restrict__ SiPF, const float* __restrict__ bv2,
    const int* __restrict__ col,    const float* __restrict__ ws,
    const ushort_t* __restrict__ wb, const ushort_t* __restrict__ xT,
    ushort_t* __restrict__ y)
{
    __shared__ __align__(16) ushort_t T1[2][4096];   // fsT [k][c]; then P~
    __shared__ __align__(16) ushort_t T2[2][4096];   // hkT; then qT
    __shared__ __align__(16) ushort_t T3[2][4096];   // hvT; then v [c][k]
    __shared__ __align__(16) ushort_t T4[2][4096];   // sipf head; then kkT

    const int bid = blockIdx.x;                      // 4096 blocks
    const int pi  = (bid & 7) * 512 + (bid >> 3);    // XCD swizzle, bijective
    const int t   = threadIdx.x;

    // ---- Phase A: stage sipf + gather fs for position p = t>>8 ----
    {
        const int p  = t >> 8;
        const int bn = pi * 2 + p;
        const int b  = bn >> 10;
        const int tt = t & 255;
        const int k  = tt & 31;
        const int cg = tt >> 5;
        if (cg < 4) {
            const int slot = (cg * 8) ^ ((k & 3) << 3);
            s8v o8 = {0, 0, 0, 0, 0, 0, 0, 0};
            if (cg == 0) {
                const float4* sp = (const float4*)(SiPF + (size_t)bn * 256 + k * 8);
                const float4 sa = sp[0], sq = sp[1];
                o8[0] = (short)f2b(sa.x); o8[1] = (short)f2b(sa.y);
                o8[2] = (short)f2b(sa.z); o8[3] = (short)f2b(sa.w);
                o8[4] = (short)f2b(sq.x); o8[5] = (short)f2b(sq.y);
                o8[6] = (short)f2b(sq.z); o8[7] = (short)f2b(sq.w);
            }
            *(s8v*)&T4[p][k * 32 + slot] = o8;
        }
        const int idxk = col[bn * K_ + k] - b * N_;
        const s8v* xrow = (const s8v*)(xT + ((size_t)(b << 10) + idxk) * 128 + cg * 16);
        const s8v f0 = xrow[0], f1 = xrow[1];
        const int base = k * 128 + cg * 16;
        const int sw   = (k & 7) << 3;
        *(s8v*)&T1[p][(base) ^ sw]     = f0;
        *(s8v*)&T1[p][(base + 8) ^ sw] = f1;
    }
    __syncthreads();

    const int wv_ = t >> 6, l = t & 63, lr = l & 15, lg = l >> 4;
    const int cw  = wv_ * 16;                        // wave channel stripe
    const f4v z4 = {0.f, 0.f, 0.f, 0.f};

    // ---- Phase A2: hk/hv for both positions (MFMA, K=8 zero-padded) ----
    {
        bf16x8 sb[4];
#pragma unroll
        for (int nt = 0; nt < 4; ++nt) {
            const int pp  = nt >> 1;
            const int row = (nt & 1) * 16 + lr;
            sb[nt] = ld8(&T4[pp][row * 32 + ((lg * 8) ^ ((row & 3) << 3))]);
        }
        const float4 bka = *(const float4*)&ws[WS_BK + cw + lg * 4];
        const float4 bva = *(const float4*)&ws[WS_BV + cw + lg * 4];
        const float Bk_[4] = {bka.x, bka.y, bka.z, bka.w};
        const float Bv_[4] = {bva.x, bva.y, bva.z, bva.w};
        const bf16x8 a1 = ld8(&wb[WK1F + (cw + lr) * 32 + lg * 8]);
        const bf16x8 a2 = ld8(&wb[WV1F + (cw + lr) * 32 + lg * 8]);
        f4v hka[4], hva[4];
#pragma unroll
        for (int nt = 0; nt < 4; ++nt) {
            hka[nt] = __builtin_amdgcn_mfma_f32_16x16x32_bf16(a1, sb[nt], z4, 0, 0, 0);
            hva[nt] = __builtin_amdgcn_mfma_f32_16x16x32_bf16(a2, sb[nt], z4, 0, 0, 0);
        }
#pragma unroll
        for (int nt = 0; nt < 4; ++nt) {
            const int pp  = nt >> 1;
            const int c0  = cw + lg * 4;
            const int kc  = (nt & 1) * 16 + lr;
            const int idx = (kc * 128 + c0) ^ ((kc & 7) << 3);
            s4v hk4, hv4;
#pragma unroll
            for (int r = 0; r < 4; ++r) {
                hk4[r] = (short)f2b(fmaxf(hka[nt][r] + Bk_[r], 0.f));
                hv4[r] = (short)f2b(fmaxf(hva[nt][r] + Bv_[r], 0.f));
            }
            *(s4v*)&T2[pp][idx] = hk4;
            *(s4v*)&T3[pp][idx] = hv4;
        }
    }
    __syncthreads();

    // ---- Phase CB: 4 GEMMs x N=64 (both positions), 64 MFMA/wave ----
    f4v ck[4], cs[4], aq[4], av[4];
#pragma unroll
    for (int nt = 0; nt < 4; ++nt) { ck[nt] = z4; cs[nt] = z4; aq[nt] = z4; av[nt] = z4; }
    __builtin_amdgcn_s_setprio(1);
#pragma unroll
    for (int kt = 0; kt < 4; ++kt) {
        const int cp0 = kt * 32 + lg * 8;
        bf16x8 bk[4], bv[4], bfr[4];
#pragma unroll
        for (int nt = 0; nt < 4; ++nt) {
            const int pp  = nt >> 1;
            const int kk_ = (nt & 1) * 16 + lr;
            const int idx = (kk_ * 128 + cp0) ^ ((lr & 7) << 3);
            bk[nt]  = ld8(&T2[pp][idx]);
            bv[nt]  = ld8(&T3[pp][idx]);
            bfr[nt] = ld8(&T1[pp][idx]);
        }
        const int c = cw + lr;
        const bf16x8 a1 = ld8(&wb[WK2B + c * 128 + cp0]);
        const bf16x8 a2 = ld8(&wb[WV2B + c * 128 + cp0]);
        const bf16x8 a3 = ld8(&wb[WQB  + c * 128 + cp0]);
        const bf16x8 a4 = ld8(&wb[WVB  + c * 128 + cp0]);
#pragma unroll
        for (int nt = 0; nt < 4; ++nt) {
            ck[nt] = __builtin_amdgcn_mfma_f32_16x16x32_bf16(a1, bk[nt],  ck[nt], 0, 0, 0);
            cs[nt] = __builtin_amdgcn_mfma_f32_16x16x32_bf16(a2, bv[nt],  cs[nt], 0, 0, 0);
            aq[nt] = __builtin_amdgcn_mfma_f32_16x16x32_bf16(a3, bfr[nt], aq[nt], 0, 0, 0);
            av[nt] = __builtin_amdgcn_mfma_f32_16x16x32_bf16(a4, bfr[nt], av[nt], 0, 0, 0);
        }
    }
    __builtin_amdgcn_s_setprio(0);
    // kk -> T4 (sipf dead since A2 barrier; disjoint per-wave rows)
#pragma unroll
    for (int nt = 0; nt < 4; ++nt) {
        const int pp  = nt >> 1;
        const int c0  = cw + lg * 4;
        const int kk_ = (nt & 1) * 16 + lr;
        const int idx = (kk_ * 128 + c0) ^ ((kk_ & 7) << 3);
        s4v ck4;
#pragma unroll
        for (int r = 0; r < 4; ++r) ck4[r] = (short)f2b(ck[nt][r]);
        *(s4v*)&T4[pp][idx] = ck4;
    }
    __syncthreads();   // all T1/T2/T3 reads complete

    // ---- q -> T2 (scale pre-folded), v = vfs*(cs+bv2) -> T3 ----
    {
        const float4 bvv = *(const float4*)&bv2[cw + lg * 4];
        const float bv2_[4] = {bvv.x, bvv.y, bvv.z, bvv.w};
#pragma unroll
        for (int nt = 0; nt < 4; ++nt) {
            const int pp  = nt >> 1;
            const int c0  = cw + lg * 4;
            const int kk_ = (nt & 1) * 16 + lr;
            const int idx = (kk_ * 128 + c0) ^ ((kk_ & 7) << 3);
            s4v q4;
#pragma unroll
            for (int r = 0; r < 4; ++r) {
                q4[r] = (short)f2b(aq[nt][r]);
                T3[pp][qx2(c0 + r, kk_)] =
                    f2b(av[nt][r] * (cs[nt][r] + bv2_[r]));
            }
            *(s4v*)&T2[pp][idx] = q4;
        }
    }
    __syncthreads();

    // ---- Phase D: attention, wave -> (position, head) ----
    // Shuffle-free softmax (R10-verified): P~=exp(s) unnormalized;
    // rs = mfma(ones, P~) lands at col=kq=lr — lane-aligned with o2 cols.
    {
        const int pp = wv_ >> 2;
        const int h  = wv_ & 3;
        const int bn = pi * 2 + pp;
        bf16x8 aqf[2], bkf[2];
#pragma unroll
        for (int mt = 0; mt < 2; ++mt)
            aqf[mt] = ld8(&T2[pp][((mt * 16 + lr) * 128 + h * 32 + lg * 8) ^ ((lr & 7) << 3)]);
#pragma unroll
        for (int nt = 0; nt < 2; ++nt)
            bkf[nt] = ld8(&T4[pp][((nt * 16 + lr) * 128 + h * 32 + lg * 8) ^ ((lr & 7) << 3)]);
        f4v s[2][2];
#pragma unroll
        for (int mt = 0; mt < 2; ++mt)
#pragma unroll
            for (int nt = 0; nt < 2; ++nt)
                s[mt][nt] = __builtin_amdgcn_mfma_f32_16x16x32_bf16(aqf[mt], bkf[nt], z4, 0, 0, 0);

        // P~ = exp(s), store unnormalized into T1 (fsT dead)
        ushort_t* P = &T1[pp][h * 1024];
#pragma unroll
        for (int mt = 0; mt < 2; ++mt)
#pragma unroll
            for (int nt = 0; nt < 2; ++nt) {
                const int kq0 = mt * 16 + lg * 4;
                const int j   = nt * 16 + lr;
#pragma unroll
                for (int r = 0; r < 4; ++r) {
                    const int kq = kq0 + r;
                    P[(kq * 32 + j) ^ ((kq & 7) << 3)] = f2b(__expf(s[mt][nt][r]));
                }
            }

        bf16x8 af[2], pb[2];
#pragma unroll
        for (int mt2 = 0; mt2 < 2; ++mt2)
            af[mt2] = ld8(&T3[pp][qx2(h * 32 + mt2 * 16 + lr, lg * 8)]);
#pragma unroll
        for (int nt2 = 0; nt2 < 2; ++nt2) {
            const int kq2 = nt2 * 16 + lr;
            pb[nt2] = ld8(&P[(kq2 * 32 + lg * 8) ^ ((lr & 7) << 3)]);
        }
        const s8v one8 = {(short)0x3F80, (short)0x3F80, (short)0x3F80, (short)0x3F80,
                          (short)0x3F80, (short)0x3F80, (short)0x3F80, (short)0x3F80};
        const bf16x8 ones = __builtin_bit_cast(bf16x8, one8);

        f4v o2[2][2], rsf[2];
        __builtin_amdgcn_s_setprio(1);
#pragma unroll
        for (int mt2 = 0; mt2 < 2; ++mt2)
#pragma unroll
            for (int nt2 = 0; nt2 < 2; ++nt2)
                o2[mt2][nt2] = __builtin_amdgcn_mfma_f32_16x16x32_bf16(af[mt2], pb[nt2], z4, 0, 0, 0);
#pragma unroll
        for (int nt2 = 0; nt2 < 2; ++nt2)
            rsf[nt2] = __builtin_amdgcn_mfma_f32_16x16x32_bf16(ones, pb[nt2], z4, 0, 0, 0);
        __builtin_amdgcn_s_setprio(0);

        const float inv0 = 1.0f / rsf[0][0];
        const float inv1 = 1.0f / rsf[1][0];

        float ym[2][4];
#pragma unroll
        for (int mt2 = 0; mt2 < 2; ++mt2)
#pragma unroll
            for (int r = 0; r < 4; ++r)
                ym[mt2][r] = fmaxf(o2[mt2][0][r] * inv0, o2[mt2][1][r] * inv1);
        // butterfly over lr bits only (lg lanes hold different channels)
#pragma unroll
        for (int m = 1; m <= 8; m <<= 1)
#pragma unroll
            for (int mt2 = 0; mt2 < 2; ++mt2)
#pragma unroll
                for (int r = 0; r < 4; ++r)
                    ym[mt2][r] = fmaxf(ym[mt2][r], __shfl_xor(ym[mt2][r], m));
        if (lr == 0) {
#pragma unroll
            for (int mt2 = 0; mt2 < 2; ++mt2) {
                unsigned long long pk = 0;
#pragma unroll
                for (int r = 0; r < 4; ++r)
                    pk |= ((unsigned long long)f2b(ym[mt2][r])) << (16 * r);
                *(unsigned long long*)&y[(size_t)bn * 128 + h * 32 + mt2 * 16 + lg * 4] = pk;
            }
        }
    }
}

// ---------------------------------------------------------------------------
// zgemm (R10 shape): 512 blocks (32 bn-rows x M-half); raw z -> d_out + stats.
// ---------------------------------------------------------------------------
__global__ __launch_bounds__(256) void zgemm_kernel(
    const ushort_t* __restrict__ wb, const ushort_t* __restrict__ xT,
    const ushort_t* __restrict__ y, float* __restrict__ ws,
    float* __restrict__ out)
{
    __shared__ __align__(16) ushort_t Bt[32 * 256];  // [bn-local][c] swizzled
    const int blk = blockIdx.x;                      // 512 blocks
    const int bn0 = (blk >> 1) * 32;
    const int mh  = (blk & 1) * 128;
    const int t   = threadIdx.x;
    {
        const int r   = t >> 3;
        const int c0  = (t & 7) * 16;
        const int bnr = bn0 + r;
        const s8v* yr = (const s8v*)(y  + (size_t)bnr * 128 + c0);
        const s8v* xr = (const s8v*)(xT + (size_t)bnr * 128 + c0);
        const s8v y0 = yr[0], y1 = yr[1], x0 = xr[0], x1 = xr[1];
        s8v d0, d1;
#pragma unroll
        for (int j = 0; j < 8; ++j) {
            d0[j] = (short)f2b(b2f((ushort_t)y0[j]) - b2f((ushort_t)x0[j]));
            d1[j] = (short)f2b(b2f((ushort_t)y1[j]) - b2f((ushort_t)x1[j]));
        }
        const int sw = (r & 7) << 3;
        *(s8v*)&Bt[(r * 256 + c0) ^ sw]           = d0;
        *(s8v*)&Bt[(r * 256 + c0 + 8) ^ sw]       = d1;
        *(s8v*)&Bt[(r * 256 + 128 + c0) ^ sw]     = x0;
        *(s8v*)&Bt[(r * 256 + 128 + c0 + 8) ^ sw] = x1;
    }
    __syncthreads();

    const int w = t >> 6, l = t & 63, lr = l & 15, lg = l >> 4;
    const f4v z4 = {0.f, 0.f, 0.f, 0.f};
    f4v acc[2][2];
#pragma unroll
    for (int mt = 0; mt < 2; ++mt)
#pragma unroll
        for (int nt = 0; nt < 2; ++nt) acc[mt][nt] = z4;

#pragma unroll
    for (int kt = 0; kt < 8; ++kt) {
        const int kc = kt * 32 + lg * 8;
        bf16x8 bf[2];
#pragma unroll
        for (int nt = 0; nt < 2; ++nt) {
            const int rl = nt * 16 + lr;
            bf[nt] = ld8(&Bt[(rl * 256 + kc) ^ ((lr & 7) << 3)]);
        }
#pragma unroll
        for (int mt = 0; mt < 2; ++mt) {
            const int o = mh + w * 32 + mt * 16 + lr;
            const bf16x8 am = ld8(&wb[WEB + o * 256 + kc]);
#pragma unroll
            for (int nt = 0; nt < 2; ++nt)
                acc[mt][nt] = __builtin_amdgcn_mfma_f32_16x16x32_bf16(am, bf[nt], acc[mt][nt], 0, 0, 0);
        }
    }

    float sm[2][4], sq[2][4];
#pragma unroll
    for (int mt = 0; mt < 2; ++mt)
#pragma unroll
        for (int r = 0; r < 4; ++r) {
            const float a0 = acc[mt][0][r], a1 = acc[mt][1][r];
            sm[mt][r] = a0 + a1;
            sq[mt][r] = a0 * a0 + a1 * a1;
        }
#pragma unroll
    for (int m = 1; m <= 8; m <<= 1)
#pragma unroll
        for (int mt = 0; mt < 2; ++mt)
#pragma unroll
            for (int r = 0; r < 4; ++r) {
                sm[mt][r] += __shfl_xor(sm[mt][r], m);
                sq[mt][r] += __shfl_xor(sq[mt][r], m);
            }
    if (lr == 0) {
#pragma unroll
        for (int mt = 0; mt < 2; ++mt)
#pragma unroll
            for (int r = 0; r < 4; ++r) {
                const int o = mh + w * 32 + mt * 16 + lg * 4 + r;
                atomicAdd(&ws[WS_ESUM + o], sm[mt][r]);
                atomicAdd(&ws[WS_ESS + o],  sq[mt][r]);
            }
    }
    const int b = bn0 >> 10;
#pragma unroll
    for (int mt = 0; mt < 2; ++mt)
#pragma unroll
        for (int r = 0; r < 4; ++r) {
            const int o = mh + w * 32 + mt * 16 + lg * 4 + r;
#pragma unroll
            for (int nt = 0; nt < 2; ++nt) {
                const int n = (bn0 + nt * 16 + lr) & (N_ - 1);
                out[((size_t)(b * COUT + o)) * N_ + n] = acc[mt][nt][r];
            }
        }
}

// ---------------------------------------------------------------------------
// apply: in-place BN1d affine + leaky on d_out.
// ---------------------------------------------------------------------------
__global__ __launch_bounds__(256) void apply_kernel(
    const float* __restrict__ ws, const float* __restrict__ gamma,
    const float* __restrict__ beta, float* __restrict__ out)
{
    const int bo = blockIdx.x;                       // (b, o)
    const int o  = bo & 255;
    const int b  = bo >> 8;
    const float mean = ws[WS_ESUM + o] * INV_BN;
    const float var  = ws[WS_ESS + o] * INV_BN - mean * mean;
    const float A  = gamma[o] * rsqrtf(var + EPSF);
    const float Bb = beta[o] - mean * A;
    float4* p = (float4*)(out + ((size_t)(b * COUT + o)) * N_);
    float4 v = p[threadIdx.x];
    float r0 = A * v.x + Bb, r1 = A * v.y + Bb;
    float r2 = A * v.z + Bb, r3 = A * v.w + Bb;
    v.x = r0 >= 0.f ? r0 : NEG * r0;
    v.y = r1 >= 0.f ? r1 : NEG * r1;
    v.z = r2 >= 0.f ? r2 : NEG * r2;
    v.w = r3 >= 0.f ? r3 : NEG * r3;
    p[threadIdx.x] = v;
}

// ---------------------------------------------------------------------------
extern "C" void kernel_launch(void* const* d_in, const int* in_sizes, int n_in,
                              void* d_out, int out_size, void* d_ws, size_t ws_size,
                              hipStream_t stream)
{
    (void)in_sizes; (void)n_in; (void)out_size; (void)ws_size;

    const float* x         = (const float*)d_in[0];
    const float* SiPF      = (const float*)d_in[1];
    const float* w_kv      = (const float*)d_in[2];
    const float* wk1       = (const float*)d_in[3];
    const float* bnk_gamma = (const float*)d_in[4];
    const float* bnk_beta  = (const float*)d_in[5];
    const float* wk2       = (const float*)d_in[6];
    const float* wv1       = (const float*)d_in[7];
    // d_in[8] = bv1: cancels inside _bn2d — unused
    const float* bnv_gamma = (const float*)d_in[9];
    const float* bnv_beta  = (const float*)d_in[10];
    const float* wv2       = (const float*)d_in[11];
    const float* bv2       = (const float*)d_in[12];
    const float* we        = (const float*)d_in[13];
    const float* bne_gamma = (const float*)d_in[14];
    const float* bne_beta  = (const float*)d_in[15];
    const int*   col       = (const int*)d_in[16];

    float*    ws = (float*)d_ws;
    ushort_t* wb = (ushort_t*)((char*)d_ws + WB_BYTE);
    ushort_t* xT = (ushort_t*)((char*)d_ws + XT_BYTE);
    ushort_t* y  = (ushort_t*)((char*)d_ws + Y_BYTE);

    prep_kernel<<<640, 256, 0, stream>>>(x, SiPF, w_kv, wk2, wv2, we, ws, wb, xT);
    prep2_kernel<<<1, 128, 0, stream>>>(wk1, wv1, bnk_gamma, bnk_beta,
                                        bnv_gamma, bnv_beta, ws, wb);
    main_kernel<<<4096, 512, 0, stream>>>(SiPF, bv2, col, ws, wb, xT, y);
    zgemm_kernel<<<512, 256, 0, stream>>>(wb, xT, y, ws, (float*)d_out);
    apply_kernel<<<2048, 256, 0, stream>>>(ws, bne_gamma, bne_beta,
                                           (float*)d_out);
}